// Round 12
// baseline (929.965 us; speedup 1.0000x reference)
//
#include <hip/hip_runtime.h>
#include <hip/hip_bf16.h>

#define N_NODES 20000
#define N_EDGES 250000
#define T_WIN   60
#define F_IN    16
#define HID     128
#define G4      512      // 4*HID
#define HEADS   4

// ---------------- ws layout (float offsets) ----------------
#define WPK_OFF    0            // 81920 ushort (LSTM W B-frags)
#define BIASC_OFF  40960        // 512
#define WPK2_OFF   41472        // 131072 ushort (GAT-lin W B-frags) = 65536 floats
#define BIASC2_OFF 107008       // 1024
#define H_OFF      108032       // 20000*128 ushort (bf16 h) = 1,280,000 floats
#define XL_OFF     1388032      // 20000*512 ushort = 5,120,000 floats
#define XR_OFF     6508032      // 20000*512 ushort
#define CNT_OFF    11628032     // 20000 ints
#define CNT2_OFF   11648032     // 20000 ints
#define BASE_OFF   11668032     // 20001 ints
#define SRT_OFF    11688033     // 250000 ints

typedef __attribute__((ext_vector_type(8))) short short8;
typedef __attribute__((ext_vector_type(8))) unsigned short ushort8;
typedef __attribute__((ext_vector_type(4))) float f32x4;
typedef __attribute__((ext_vector_type(4))) unsigned short ushortx4;

// fast activations: v_rcp_f32 (rel err ~2^-22) instead of IEEE divide
__device__ __forceinline__ float fsigmoid(float x) {
    return __builtin_amdgcn_rcpf(1.0f + __expf(-x));
}
__device__ __forceinline__ float ftanh(float x) {
    return fmaf(2.0f, __builtin_amdgcn_rcpf(1.0f + __expf(-2.0f * x)), -1.0f);
}

__device__ __forceinline__ unsigned short f2bf(float f) {
    unsigned u = __float_as_uint(f);
    u += 0x7FFFu + ((u >> 16) & 1u);   // RNE
    return (unsigned short)(u >> 16);
}
__device__ __forceinline__ float bf2f(unsigned short u) {
    return __uint_as_float((unsigned)u << 16);
}
__device__ __forceinline__ unsigned cvt_pk_bf16(float a, float b) {
    unsigned r;
    asm("v_cvt_pk_bf16_f32 %0, %1, %2" : "=v"(r) : "v"(a), "v"(b));
    return r;
}

// ---------------- pack LSTM W into MFMA B-fragment layout ----------------
// Wpk index = (((g*8+ht)*5+kt)*64 + lane)*8 + i
// element: k = kt*32 + (lane>>4)*8 + i ; col = g*128 + ht*16 + (lane&15)
// B[k][col] = k<128 ? Whh[col][k] : (k<144 ? Wih[col][k-128] : 0)
__global__ void pack_w_kernel(const float* __restrict__ Wih, const float* __restrict__ Whh,
                              const float* __restrict__ bih, const float* __restrict__ bhh,
                              unsigned short* __restrict__ wpk, float* __restrict__ biasc)
{
    int idx = blockIdx.x * 256 + threadIdx.x;
    if (idx < 81920) {
        int i  = idx & 7;
        int l  = (idx >> 3) & 63;
        int r  = idx >> 9;
        int kt = r % 5;
        int gh = r / 5;
        int ht = gh & 7;
        int g  = gh >> 3;
        int k   = kt * 32 + (l >> 4) * 8 + i;
        int col = g * 128 + ht * 16 + (l & 15);
        float v = 0.0f;
        if (k < 128)      v = Whh[col * 128 + k];
        else if (k < 144) v = Wih[col * 16 + (k - 128)];
        wpk[idx] = f2bf(v);
    }
    if (idx < G4) biasc[idx] = bih[idx] + bhh[idx];
}

// ---------------- pack GAT lin W (Wl|Wr -> [128 k][1024 cols]) into B-frags ----------------
__global__ void pack_w2_kernel(const float* __restrict__ Wl, const float* __restrict__ bl,
                               const float* __restrict__ Wr, const float* __restrict__ br,
                               unsigned short* __restrict__ wpk2, float* __restrict__ biasc2)
{
    int idx = blockIdx.x * 256 + threadIdx.x;
    if (idx < 131072) {
        int i  = idx & 7;
        int l  = (idx >> 3) & 63;
        int f  = idx >> 9;       // ht*4 + kt
        int kt = f & 3;
        int ht = f >> 2;
        int k   = kt * 32 + (l >> 4) * 8 + i;
        int col = ht * 16 + (l & 15);
        float v = (col < 512) ? Wl[col * 128 + k] : Wr[(col - 512) * 128 + k];
        wpk2[idx] = f2bf(v);
    }
    if (idx < 1024) biasc2[idx] = (idx < 512) ? bl[idx] : br[idx - 512];
}

// ---------------- LSTM: MFMA bf16, 96 nodes/block, 1024 threads = 16 waves ----------------
// 16 waves in ONE block -> 4 waves/SIMD guaranteed co-resident.
// REGISTER CONTRACT (r9/r10/r11 lesson): __launch_bounds__' 2nd arg is a MINIMUM
// occupancy demand — it can only LOWER the VGPR cap, never raise it. The compiler's
// default for a 1024-thread workgroup targets 8 waves/EU -> 64-VGPR cap -> the 80-reg
// persistent W-frags spilled to scratch (644 MB reads/dispatch, 833 us). The knob that
// RAISES the budget is the max side of amdgpu_waves_per_eu: (1,4) => at most 4 waves/EU
// (exactly one 16-wave workgroup per CU) => VGPR budget 512/4 = 128, fits ~96-reg need.
// Time loop unroll 1 ON PURPOSE (r4: unroll 2 spilled ~96 MB to scratch).
#define BMM  96
#define ASTR 384

__global__ __launch_bounds__(1024)
__attribute__((amdgpu_waves_per_eu(1, 4)))
void lstm_mfma_kernel(
    const float* __restrict__ x, const unsigned short* __restrict__ wpk,
    const float* __restrict__ biasc, unsigned short* __restrict__ hout)
{
    __shared__ __align__(16) unsigned char Abuf[2][BMM * ASTR];   // 2 x 36864 B
    const int tid  = threadIdx.x;
    const int wave = tid >> 6;        // 0..15
    const int lane = tid & 63;
    const int mg   = wave >> 3;       // M-half: 0 -> tiles 0..2, 1 -> tiles 3..5
    const int ht   = wave & 7;        // col tile
    const int n0   = blockIdx.x * BMM;

    {
        f32x4 z = {0.0f, 0.0f, 0.0f, 0.0f};
        unsigned char* ab = &Abuf[0][0];
        for (int i = tid; i < 2 * BMM * ASTR / 16; i += 1024)
            *(f32x4*)&ab[i * 16] = z;
    }

    // persistent B-fragments: col tile ht, all 4 gates
    short8 wf[4][5];
#pragma unroll
    for (int g = 0; g < 4; ++g)
#pragma unroll
        for (int kt = 0; kt < 5; ++kt)
            wf[g][kt] = *(const short8*)&wpk[((((g * 8 + ht) * 5) + kt) * 64 + lane) * 8];

    float bias[4];
#pragma unroll
    for (int g = 0; g < 4; ++g) bias[g] = biasc[g * 128 + ht * 16 + (lane & 15)];

    float c[3][4];
#pragma unroll
    for (int mt = 0; mt < 3; ++mt)
#pragma unroll
        for (int r = 0; r < 4; ++r) c[mt][r] = 0.0f;

    const int  xnode   = tid >> 2;          // 0..95 for tid<384
    const int  xq      = tid & 3;
    const bool xactive = (tid < BMM * 4) && (n0 + xnode < N_NODES);  // waves 0-5 stage x
    const int  xoff    = (256 + xq * 8) ^ ((xnode & 7) << 4);
    const int  colw    = ht * 16 + (lane & 15);
    const float* xptr  = &x[(size_t)(n0 + xnode) * (T_WIN * F_IN) + xq * 4];

    __syncthreads();

    if (xactive) {
        float4 v = *(const float4*)xptr;
        ushortx4 b;
        b.x = f2bf(v.x); b.y = f2bf(v.y); b.z = f2bf(v.z); b.w = f2bf(v.w);
        *(ushortx4*)&Abuf[0][xnode * ASTR + xoff] = b;
    }
    __syncthreads();

#pragma unroll 1
    for (int t = 0; t < T_WIN; ++t) {
        const int cur = t & 1;
        const int nxt = cur ^ 1;

        float4 xv = {0.0f, 0.0f, 0.0f, 0.0f};
        if (xactive && t + 1 < T_WIN) xv = *(const float4*)(xptr + (t + 1) * F_IN);

        // per-mt: ds_read -> 20 MFMA -> activation (act(mt) overlaps MFMA(mt+1))
#pragma unroll
        for (int mt = 0; mt < 3; ++mt) {
            const int gtile = mg * 3 + mt;
            const int row = gtile * 16 + (lane & 15);
            const int rsw = (row & 7) << 4;
            short8 af[5];
#pragma unroll
            for (int kt = 0; kt < 5; ++kt)
                af[kt] = *(const short8*)&Abuf[cur][row * ASTR + ((kt * 64 + (lane >> 4) * 16) ^ rsw)];

            f32x4 ag[4];
#pragma unroll
            for (int g = 0; g < 4; ++g) {
                f32x4 a = {bias[g], bias[g], bias[g], bias[g]};
                ag[g] = a;
            }
#pragma unroll
            for (int kt = 0; kt < 5; ++kt)
#pragma unroll
                for (int g = 0; g < 4; ++g)
                    ag[g] = __builtin_amdgcn_mfma_f32_16x16x32_bf16(af[kt], wf[g][kt], ag[g], 0, 0, 0);

#pragma unroll
            for (int rp = 0; rp < 2; ++rp) {
                float hh[2];
#pragma unroll
                for (int r2 = 0; r2 < 2; ++r2) {
                    const int r = rp * 2 + r2;
                    float ig = fsigmoid(ag[0][r]);
                    float fg = fsigmoid(ag[1][r]);
                    float gg = ftanh(ag[2][r]);
                    float og = fsigmoid(ag[3][r]);
                    float cn = fg * c[mt][r] + ig * gg;
                    c[mt][r] = cn;
                    hh[r2] = og * ftanh(cn);
                }
                const unsigned pk = cvt_pk_bf16(hh[0], hh[1]);
                const int node0 = gtile * 16 + (lane >> 4) * 4 + rp * 2;
                const int node1 = node0 + 1;
                if (t < T_WIN - 1) {
                    *(unsigned short*)&Abuf[nxt][node0 * ASTR + ((colw * 2) ^ ((node0 & 7) << 4))] =
                        (unsigned short)pk;
                    *(unsigned short*)&Abuf[nxt][node1 * ASTR + ((colw * 2) ^ ((node1 & 7) << 4))] =
                        (unsigned short)(pk >> 16);
                } else {
                    if (n0 + node0 < N_NODES)
                        hout[(size_t)(n0 + node0) * HID + colw] = (unsigned short)pk;
                    if (n0 + node1 < N_NODES)
                        hout[(size_t)(n0 + node1) * HID + colw] = (unsigned short)(pk >> 16);
                }
            }
        }

        if (xactive && t + 1 < T_WIN) {
            ushortx4 b;
            b.x = f2bf(xv.x); b.y = f2bf(xv.y); b.z = f2bf(xv.z); b.w = f2bf(xv.w);
            *(ushortx4*)&Abuf[nxt][xnode * ASTR + xoff] = b;
        }
        __syncthreads();
    }
}

// ---------------- GEMM2 (MFMA): [xl|xr] = h @ [Wl|Wr]^T + bias, bf16 in/out ----------------
#define G2_BM 64
__global__ __launch_bounds__(256) void gemm2_mfma_kernel(
    const unsigned short* __restrict__ hbf,   // [20000][128] bf16
    const unsigned short* __restrict__ wpk2,  // packed B-frags
    const float* __restrict__ biasc2,         // [1024]
    unsigned short* __restrict__ xl, unsigned short* __restrict__ xr)
{
    __shared__ __align__(16) unsigned char Hs[G2_BM * 256];  // [64 rows][128 bf16], XOR-swizzled
    const int tid  = threadIdx.x;
    const int wave = tid >> 6;
    const int lane = tid & 63;
    const int mb = blockIdx.x >> 2;
    const int nb = blockIdx.x & 3;     // 4 col-blocks of 256 (0,1 -> xl; 2,3 -> xr)
    const int n0 = mb * G2_BM;

#pragma unroll
    for (int q = 0; q < 4; ++q) {
        int fi = tid + q * 256;
        int node = fi >> 4;
        int kb = (fi & 15) * 16;
        ushort8 v = {0, 0, 0, 0, 0, 0, 0, 0};
        if (n0 + node < N_NODES) v = *(const ushort8*)&hbf[(size_t)(n0 + node) * HID + kb / 2];
        *(ushort8*)&Hs[node * 256 + (kb ^ ((node & 7) << 4))] = v;
    }
    __syncthreads();

    const int colt0 = nb * 16 + wave * 4;
    float bias4[4];
#pragma unroll
    for (int ct = 0; ct < 4; ++ct)
        bias4[ct] = biasc2[(colt0 + ct) * 16 + (lane & 15)];

    f32x4 acc[4][4];
#pragma unroll
    for (int mt = 0; mt < 4; ++mt)
#pragma unroll
        for (int ct = 0; ct < 4; ++ct) {
            f32x4 a = {bias4[ct], bias4[ct], bias4[ct], bias4[ct]};
            acc[mt][ct] = a;
        }

#pragma unroll
    for (int kt = 0; kt < 4; ++kt) {
        short8 wf[4];
#pragma unroll
        for (int ct = 0; ct < 4; ++ct)
            wf[ct] = *(const short8*)&wpk2[(((colt0 + ct) * 4 + kt) * 64 + lane) * 8];
        short8 af[4];
        const int kbyte = kt * 64 + (lane >> 4) * 16;
#pragma unroll
        for (int mt = 0; mt < 4; ++mt) {
            int row = mt * 16 + (lane & 15);
            af[mt] = *(const short8*)&Hs[row * 256 + (kbyte ^ ((row & 7) << 4))];
        }
#pragma unroll
        for (int mt = 0; mt < 4; ++mt)
#pragma unroll
            for (int ct = 0; ct < 4; ++ct)
                acc[mt][ct] = __builtin_amdgcn_mfma_f32_16x16x32_bf16(af[mt], wf[ct], acc[mt][ct], 0, 0, 0);
    }

    unsigned short* outp = (nb < 2) ? xl : xr;
    const int lcol = (nb & 1) * 256 + wave * 64 + (lane & 15);
#pragma unroll
    for (int mt = 0; mt < 4; ++mt)
#pragma unroll
        for (int ct = 0; ct < 4; ++ct)
#pragma unroll
            for (int r = 0; r < 4; ++r) {
                int row = n0 + mt * 16 + (lane >> 4) * 4 + r;
                if (row < N_NODES)
                    outp[(size_t)row * G4 + lcol + ct * 16] = f2bf(acc[mt][ct][r]);
            }
}

// ---------------- edge sort (counting sort by dst) ----------------
__global__ void count_kernel(const int* __restrict__ ei, int* __restrict__ cnt)
{
    int e = blockIdx.x * 256 + threadIdx.x;
    if (e < N_EDGES) {
        int dst = ei[N_EDGES + e];
        if (dst >= 0 && dst < N_NODES) atomicAdd(&cnt[dst], 1);
    }
}

__global__ void scan_kernel(const int* __restrict__ cnt, int* __restrict__ base)
{
    __shared__ int ps[256];
    const int tid = threadIdx.x;
    const int CH = (N_NODES + 255) / 256;
    int s = 0;
    for (int i = 0; i < CH; ++i) {
        int idx = tid * CH + i;
        if (idx < N_NODES) s += cnt[idx];
    }
    ps[tid] = s;
    __syncthreads();
    for (int off = 1; off < 256; off <<= 1) {
        int v = (tid >= off) ? ps[tid - off] : 0;
        __syncthreads();
        ps[tid] += v;
        __syncthreads();
    }
    int run = (tid > 0) ? ps[tid - 1] : 0;
    for (int i = 0; i < CH; ++i) {
        int idx = tid * CH + i;
        if (idx < N_NODES) { base[idx] = run; run += cnt[idx]; }
    }
    if (tid == 255) base[N_NODES] = ps[255];
}

__global__ void scatter_kernel(const int* __restrict__ ei, const int* __restrict__ base,
                               int* __restrict__ cnt2, int* __restrict__ srt)
{
    int e = blockIdx.x * 256 + threadIdx.x;
    if (e < N_EDGES) {
        int dst = ei[N_EDGES + e];
        int src = ei[e];
        if (dst >= 0 && dst < N_NODES) {
            int pos = base[dst] + atomicAdd(&cnt2[dst], 1);
            srt[pos] = src;
        }
    }
}

// ---------------- GATv2 aggregate: one wave per dst, online softmax (bf16 xl/xr) ----------------
__global__ __launch_bounds__(256) void gat_kernel(
    const unsigned short* __restrict__ xl, const unsigned short* __restrict__ xr,
    const float* __restrict__ att, const float* __restrict__ gbias,
    const float* __restrict__ Wp, const float* __restrict__ bp,
    const int* __restrict__ base, const int* __restrict__ srt,
    float* __restrict__ out)
{
    const int wave = threadIdx.x >> 6;
    const int lane = threadIdx.x & 63;
    const int dst = blockIdx.x * 4 + wave;
    if (dst >= N_NODES) return;

    ushort8 xr8 = *(const ushort8*)&xr[(size_t)dst * G4 + lane * 8];
    float xrv[8];
#pragma unroll
    for (int i = 0; i < 8; ++i) xrv[i] = bf2f(xr8[i]);
    float4 at0 = *(const float4*)&att[lane * 8];
    float4 at1 = *(const float4*)&att[lane * 8 + 4];
    float atv[8] = {at0.x, at0.y, at0.z, at0.w, at1.x, at1.y, at1.z, at1.w};

    float m = -INFINITY, d = 0.0f;
    float acc[8];
#pragma unroll
    for (int i = 0; i < 8; ++i) acc[i] = 0.0f;

    const int b0 = base[dst], b1 = base[dst + 1];
    for (int idx = b0; idx <= b1; ++idx) {
        int src = (idx < b1) ? srt[idx] : dst;
        ushort8 v8 = *(const ushort8*)&xl[(size_t)src * G4 + lane * 8];
        float xv[8];
#pragma unroll
        for (int i = 0; i < 8; ++i) xv[i] = bf2f(v8[i]);
        float p = 0.0f;
#pragma unroll
        for (int i = 0; i < 8; ++i) {
            float e = xv[i] + xrv[i];
            e = (e > 0.0f) ? e : 0.2f * e;
            p = fmaf(atv[i], e, p);
        }
        p += __shfl_xor(p, 1);
        p += __shfl_xor(p, 2);
        p += __shfl_xor(p, 4);
        p += __shfl_xor(p, 8);
        float mn = fmaxf(m, p);
        float scale = __expf(m - mn);
        float al = __expf(p - mn);
        d = d * scale + al;
#pragma unroll
        for (int i = 0; i < 8; ++i) acc[i] = fmaf(al, xv[i], acc[i] * scale);
        m = mn;
    }

    float inv = 1.0f / d;
    float o[8];
#pragma unroll
    for (int i = 0; i < 8; ++i) o[i] = acc[i] * inv;
#pragma unroll
    for (int i = 0; i < 8; ++i) {
        o[i] += __shfl_xor(o[i], 16);
        o[i] += __shfl_xor(o[i], 32);
    }
    const int c0 = (lane & 15) * 8;
    float psum = 0.0f;
#pragma unroll
    for (int i = 0; i < 8; ++i) {
        float s = 0.25f * o[i] + gbias[c0 + i];
        s = (s > 0.0f) ? s : (__expf(s) - 1.0f);
        psum = fmaf(s, Wp[c0 + i], psum);
    }
    psum += __shfl_xor(psum, 1);
    psum += __shfl_xor(psum, 2);
    psum += __shfl_xor(psum, 4);
    psum += __shfl_xor(psum, 8);
    if (lane == 0) out[dst] = psum + bp[0];
}

// ---------------- launch ----------------
extern "C" void kernel_launch(void* const* d_in, const int* in_sizes, int n_in,
                              void* d_out, int out_size, void* d_ws, size_t ws_size,
                              hipStream_t stream)
{
    const float* x        = (const float*)d_in[0];
    const int* ei         = (const int*)d_in[1];     // int32 per harness contract
    const float* Wih      = (const float*)d_in[2];
    const float* Whh      = (const float*)d_in[3];
    const float* bih      = (const float*)d_in[4];
    const float* bhh      = (const float*)d_in[5];
    const float* Wl       = (const float*)d_in[6];
    const float* bl       = (const float*)d_in[7];
    const float* Wr       = (const float*)d_in[8];
    const float* br       = (const float*)d_in[9];
    const float* att      = (const float*)d_in[10];
    const float* gbias    = (const float*)d_in[11];
    const float* Wp       = (const float*)d_in[12];
    const float* bp       = (const float*)d_in[13];
    float* out            = (float*)d_out;

    float* ws             = (float*)d_ws;
    unsigned short* wpk   = (unsigned short*)(ws + WPK_OFF);
    float* bsc            = ws + BIASC_OFF;
    unsigned short* wpk2  = (unsigned short*)(ws + WPK2_OFF);
    float* bsc2           = ws + BIASC2_OFF;
    unsigned short* h     = (unsigned short*)(ws + H_OFF);
    unsigned short* xlb   = (unsigned short*)(ws + XL_OFF);
    unsigned short* xrb   = (unsigned short*)(ws + XR_OFF);
    int* cnt    = (int*)(ws + CNT_OFF);
    int* cnt2   = (int*)(ws + CNT2_OFF);
    int* base   = (int*)(ws + BASE_OFF);
    int* srt    = (int*)(ws + SRT_OFF);

    hipMemsetAsync(cnt, 0, 2 * N_NODES * sizeof(int), stream);

    pack_w_kernel<<<320, 256, 0, stream>>>(Wih, Whh, bih, bhh, wpk, bsc);
    pack_w2_kernel<<<512, 256, 0, stream>>>(Wl, bl, Wr, br, wpk2, bsc2);
    count_kernel<<<(N_EDGES + 255) / 256, 256, 0, stream>>>(ei, cnt);
    scan_kernel<<<1, 256, 0, stream>>>(cnt, base);
    scatter_kernel<<<(N_EDGES + 255) / 256, 256, 0, stream>>>(ei, base, cnt2, srt);

    lstm_mfma_kernel<<<(N_NODES + BMM - 1) / BMM, 1024, 0, stream>>>(x, wpk, bsc, h);
    gemm2_mfma_kernel<<<((N_NODES + G2_BM - 1) / G2_BM) * 4, 256, 0, stream>>>(h, wpk2, bsc2, xlb, xrb);
    gat_kernel<<<(N_NODES + 3) / 4, 256, 0, stream>>>(xlb, xrb, att, gbias, Wp, bp, base, srt, out);
}

// Round 13
// 393.300 us; speedup vs baseline: 2.3645x; 2.3645x over previous
//
#include <hip/hip_runtime.h>
#include <hip/hip_bf16.h>

#define N_NODES 20000
#define N_EDGES 250000
#define T_WIN   60
#define F_IN    16
#define HID     128
#define G4      512      // 4*HID
#define HEADS   4

// ---------------- ws layout (float offsets) ----------------
#define WPK_OFF    0            // 81920 ushort (LSTM W B-frags)
#define BIASC_OFF  40960        // 512
#define WPK2_OFF   41472        // 131072 ushort (GAT-lin W B-frags) = 65536 floats
#define BIASC2_OFF 107008       // 1024
#define H_OFF      108032       // 20000*128 ushort (bf16 h) = 1,280,000 floats
#define XL_OFF     1388032      // 20000*512 ushort = 5,120,000 floats
#define XR_OFF     6508032      // 20000*512 ushort
#define CNT_OFF    11628032     // 20000 ints
#define CNT2_OFF   11648032     // 20000 ints
#define BASE_OFF   11668032     // 20001 ints
#define SRT_OFF    11688033     // 250000 ints

typedef __attribute__((ext_vector_type(8))) short short8;
typedef __attribute__((ext_vector_type(8))) unsigned short ushort8;
typedef __attribute__((ext_vector_type(4))) float f32x4;
typedef __attribute__((ext_vector_type(4))) unsigned short ushortx4;

// fast activations: v_rcp_f32 (rel err ~2^-22) instead of IEEE divide
__device__ __forceinline__ float fsigmoid(float x) {
    return __builtin_amdgcn_rcpf(1.0f + __expf(-x));
}
__device__ __forceinline__ float ftanh(float x) {
    return fmaf(2.0f, __builtin_amdgcn_rcpf(1.0f + __expf(-2.0f * x)), -1.0f);
}

__device__ __forceinline__ unsigned short f2bf(float f) {
    unsigned u = __float_as_uint(f);
    u += 0x7FFFu + ((u >> 16) & 1u);   // RNE
    return (unsigned short)(u >> 16);
}
__device__ __forceinline__ float bf2f(unsigned short u) {
    return __uint_as_float((unsigned)u << 16);
}
__device__ __forceinline__ unsigned cvt_pk_bf16(float a, float b) {
    unsigned r;
    asm("v_cvt_pk_bf16_f32 %0, %1, %2" : "=v"(r) : "v"(a), "v"(b));
    return r;
}

// ---------------- pack LSTM W into MFMA B-fragment layout ----------------
// Wpk index = (((g*8+ht)*5+kt)*64 + lane)*8 + i
// element: k = kt*32 + (lane>>4)*8 + i ; col = g*128 + ht*16 + (lane&15)
// B[k][col] = k<128 ? Whh[col][k] : (k<144 ? Wih[col][k-128] : 0)
__global__ void pack_w_kernel(const float* __restrict__ Wih, const float* __restrict__ Whh,
                              const float* __restrict__ bih, const float* __restrict__ bhh,
                              unsigned short* __restrict__ wpk, float* __restrict__ biasc)
{
    int idx = blockIdx.x * 256 + threadIdx.x;
    if (idx < 81920) {
        int i  = idx & 7;
        int l  = (idx >> 3) & 63;
        int r  = idx >> 9;
        int kt = r % 5;
        int gh = r / 5;
        int ht = gh & 7;
        int g  = gh >> 3;
        int k   = kt * 32 + (l >> 4) * 8 + i;
        int col = g * 128 + ht * 16 + (l & 15);
        float v = 0.0f;
        if (k < 128)      v = Whh[col * 128 + k];
        else if (k < 144) v = Wih[col * 16 + (k - 128)];
        wpk[idx] = f2bf(v);
    }
    if (idx < G4) biasc[idx] = bih[idx] + bhh[idx];
}

// ---------------- pack GAT lin W (Wl|Wr -> [128 k][1024 cols]) into B-frags ----------------
__global__ void pack_w2_kernel(const float* __restrict__ Wl, const float* __restrict__ bl,
                               const float* __restrict__ Wr, const float* __restrict__ br,
                               unsigned short* __restrict__ wpk2, float* __restrict__ biasc2)
{
    int idx = blockIdx.x * 256 + threadIdx.x;
    if (idx < 131072) {
        int i  = idx & 7;
        int l  = (idx >> 3) & 63;
        int f  = idx >> 9;       // ht*4 + kt
        int kt = f & 3;
        int ht = f >> 2;
        int k   = kt * 32 + (l >> 4) * 8 + i;
        int col = ht * 16 + (l & 15);
        float v = (col < 512) ? Wl[col * 128 + k] : Wr[(col - 512) * 128 + k];
        wpk2[idx] = f2bf(v);
    }
    if (idx < 1024) biasc2[idx] = (idx < 512) ? bl[idx] : br[idx - 512];
}

// ---------------- LSTM: MFMA bf16, 80 nodes/block, 250 blocks (r6-exact, 296 us) ----------------
// OCCUPANCY VERDICT (r8-r12): 512-thread blocks never co-schedule 2/CU on this setup;
// 1024-thread blocks are hard-capped at 64 VGPR (launch_bounds 2nd arg / waves_per_eu
// annotations all no-ops) -> persistent W spills. 8 waves @ 512 threads, 1 block/CU,
// VGPR ~120 is the local optimum. Time loop unroll 1 ON PURPOSE (r4 spill).
#define BMM  80
#define ASTR 384

__global__ __launch_bounds__(512) void lstm_mfma_kernel(
    const float* __restrict__ x, const unsigned short* __restrict__ wpk,
    const float* __restrict__ biasc, unsigned short* __restrict__ hout)
{
    __shared__ __align__(16) unsigned char Abuf[2][BMM * ASTR];
    const int tid  = threadIdx.x;
    const int wave = tid >> 6;
    const int lane = tid & 63;
    const int n0   = blockIdx.x * BMM;

    {
        f32x4 z = {0.0f, 0.0f, 0.0f, 0.0f};
        unsigned char* ab = &Abuf[0][0];
        for (int i = tid; i < 2 * BMM * ASTR / 16; i += 512)
            *(f32x4*)&ab[i * 16] = z;
    }

    // persistent B-fragments: wave w owns hid cols [w*16, w*16+16) for all 4 gates
    short8 wf[4][5];
#pragma unroll
    for (int g = 0; g < 4; ++g)
#pragma unroll
        for (int kt = 0; kt < 5; ++kt)
            wf[g][kt] = *(const short8*)&wpk[((((g * 8 + wave) * 5) + kt) * 64 + lane) * 8];

    float bias[4];
#pragma unroll
    for (int g = 0; g < 4; ++g) bias[g] = biasc[g * 128 + wave * 16 + (lane & 15)];

    float c[5][4];
#pragma unroll
    for (int mt = 0; mt < 5; ++mt)
#pragma unroll
        for (int r = 0; r < 4; ++r) c[mt][r] = 0.0f;

    const int  xnode   = tid >> 2;
    const int  xq      = tid & 3;
    const bool xactive = (tid < BMM * 4);
    const int  xoff    = (256 + xq * 8) ^ ((xnode & 7) << 4);
    const int  colw    = wave * 16 + (lane & 15);
    const float* xptr  = &x[(size_t)(n0 + xnode) * (T_WIN * F_IN) + xq * 4];

    __syncthreads();

    if (xactive) {
        float4 v = *(const float4*)xptr;
        ushortx4 b;
        b.x = f2bf(v.x); b.y = f2bf(v.y); b.z = f2bf(v.z); b.w = f2bf(v.w);
        *(ushortx4*)&Abuf[0][xnode * ASTR + xoff] = b;
    }
    __syncthreads();

#pragma unroll 1
    for (int t = 0; t < T_WIN; ++t) {
        const int cur = t & 1;
        const int nxt = cur ^ 1;

        float4 xv = {0.0f, 0.0f, 0.0f, 0.0f};
        if (xactive && t + 1 < T_WIN) xv = *(const float4*)(xptr + (t + 1) * F_IN);

        // per-mt: ds_read -> 20 MFMA -> activation (act(mt) overlaps MFMA(mt+1))
#pragma unroll
        for (int mt = 0; mt < 5; ++mt) {
            const int row = mt * 16 + (lane & 15);
            const int rsw = (row & 7) << 4;
            short8 af[5];
#pragma unroll
            for (int kt = 0; kt < 5; ++kt)
                af[kt] = *(const short8*)&Abuf[cur][row * ASTR + ((kt * 64 + (lane >> 4) * 16) ^ rsw)];

            f32x4 ag[4];
#pragma unroll
            for (int g = 0; g < 4; ++g) {
                f32x4 a = {bias[g], bias[g], bias[g], bias[g]};
                ag[g] = a;
            }
#pragma unroll
            for (int kt = 0; kt < 5; ++kt)
#pragma unroll
                for (int g = 0; g < 4; ++g)
                    ag[g] = __builtin_amdgcn_mfma_f32_16x16x32_bf16(af[kt], wf[g][kt], ag[g], 0, 0, 0);

#pragma unroll
            for (int rp = 0; rp < 2; ++rp) {
                float hh[2];
#pragma unroll
                for (int r2 = 0; r2 < 2; ++r2) {
                    const int r = rp * 2 + r2;
                    float ig = fsigmoid(ag[0][r]);
                    float fg = fsigmoid(ag[1][r]);
                    float gg = ftanh(ag[2][r]);
                    float og = fsigmoid(ag[3][r]);
                    float cn = fg * c[mt][r] + ig * gg;
                    c[mt][r] = cn;
                    hh[r2] = og * ftanh(cn);
                }
                const unsigned pk = cvt_pk_bf16(hh[0], hh[1]);
                const int node0 = mt * 16 + (lane >> 4) * 4 + rp * 2;
                const int node1 = node0 + 1;
                if (t < T_WIN - 1) {
                    *(unsigned short*)&Abuf[nxt][node0 * ASTR + ((colw * 2) ^ ((node0 & 7) << 4))] =
                        (unsigned short)pk;
                    *(unsigned short*)&Abuf[nxt][node1 * ASTR + ((colw * 2) ^ ((node1 & 7) << 4))] =
                        (unsigned short)(pk >> 16);
                } else {
                    hout[(size_t)(n0 + node0) * HID + colw] = (unsigned short)pk;
                    hout[(size_t)(n0 + node1) * HID + colw] = (unsigned short)(pk >> 16);
                }
            }
        }

        if (xactive && t + 1 < T_WIN) {
            ushortx4 b;
            b.x = f2bf(xv.x); b.y = f2bf(xv.y); b.z = f2bf(xv.z); b.w = f2bf(xv.w);
            *(ushortx4*)&Abuf[nxt][xnode * ASTR + xoff] = b;
        }
        __syncthreads();
    }
}

// ---------------- GEMM2 (MFMA): [xl|xr] = h @ [Wl|Wr]^T + bias, bf16 in/out ----------------
#define G2_BM 64
__global__ __launch_bounds__(256) void gemm2_mfma_kernel(
    const unsigned short* __restrict__ hbf,   // [20000][128] bf16
    const unsigned short* __restrict__ wpk2,  // packed B-frags
    const float* __restrict__ biasc2,         // [1024]
    unsigned short* __restrict__ xl, unsigned short* __restrict__ xr)
{
    __shared__ __align__(16) unsigned char Hs[G2_BM * 256];  // [64 rows][128 bf16], XOR-swizzled
    const int tid  = threadIdx.x;
    const int wave = tid >> 6;
    const int lane = tid & 63;
    const int mb = blockIdx.x >> 2;
    const int nb = blockIdx.x & 3;     // 4 col-blocks of 256 (0,1 -> xl; 2,3 -> xr)
    const int n0 = mb * G2_BM;

#pragma unroll
    for (int q = 0; q < 4; ++q) {
        int fi = tid + q * 256;
        int node = fi >> 4;
        int kb = (fi & 15) * 16;
        ushort8 v = {0, 0, 0, 0, 0, 0, 0, 0};
        if (n0 + node < N_NODES) v = *(const ushort8*)&hbf[(size_t)(n0 + node) * HID + kb / 2];
        *(ushort8*)&Hs[node * 256 + (kb ^ ((node & 7) << 4))] = v;
    }
    __syncthreads();

    const int colt0 = nb * 16 + wave * 4;
    float bias4[4];
#pragma unroll
    for (int ct = 0; ct < 4; ++ct)
        bias4[ct] = biasc2[(colt0 + ct) * 16 + (lane & 15)];

    f32x4 acc[4][4];
#pragma unroll
    for (int mt = 0; mt < 4; ++mt)
#pragma unroll
        for (int ct = 0; ct < 4; ++ct) {
            f32x4 a = {bias4[ct], bias4[ct], bias4[ct], bias4[ct]};
            acc[mt][ct] = a;
        }

#pragma unroll
    for (int kt = 0; kt < 4; ++kt) {
        short8 wf[4];
#pragma unroll
        for (int ct = 0; ct < 4; ++ct)
            wf[ct] = *(const short8*)&wpk2[(((colt0 + ct) * 4 + kt) * 64 + lane) * 8];
        short8 af[4];
        const int kbyte = kt * 64 + (lane >> 4) * 16;
#pragma unroll
        for (int mt = 0; mt < 4; ++mt) {
            int row = mt * 16 + (lane & 15);
            af[mt] = *(const short8*)&Hs[row * 256 + (kbyte ^ ((row & 7) << 4))];
        }
#pragma unroll
        for (int mt = 0; mt < 4; ++mt)
#pragma unroll
            for (int ct = 0; ct < 4; ++ct)
                acc[mt][ct] = __builtin_amdgcn_mfma_f32_16x16x32_bf16(af[mt], wf[ct], acc[mt][ct], 0, 0, 0);
    }

    unsigned short* outp = (nb < 2) ? xl : xr;
    const int lcol = (nb & 1) * 256 + wave * 64 + (lane & 15);
#pragma unroll
    for (int mt = 0; mt < 4; ++mt)
#pragma unroll
        for (int ct = 0; ct < 4; ++ct)
#pragma unroll
            for (int r = 0; r < 4; ++r) {
                int row = n0 + mt * 16 + (lane >> 4) * 4 + r;
                if (row < N_NODES)
                    outp[(size_t)row * G4 + lcol + ct * 16] = f2bf(acc[mt][ct][r]);
            }
}

// ---------------- edge sort (counting sort by dst) ----------------
__global__ void count_kernel(const int* __restrict__ ei, int* __restrict__ cnt)
{
    int e = blockIdx.x * 256 + threadIdx.x;
    if (e < N_EDGES) {
        int dst = ei[N_EDGES + e];
        if (dst >= 0 && dst < N_NODES) atomicAdd(&cnt[dst], 1);
    }
}

#define SCAN_NT 1024
__global__ __launch_bounds__(SCAN_NT) void scan_kernel(const int* __restrict__ cnt, int* __restrict__ base)
{
    __shared__ int ps[SCAN_NT];
    const int tid = threadIdx.x;
    const int CH = (N_NODES + SCAN_NT - 1) / SCAN_NT;  // 20
    int s = 0;
    for (int i = 0; i < CH; ++i) {
        int idx = tid * CH + i;
        if (idx < N_NODES) s += cnt[idx];
    }
    ps[tid] = s;
    __syncthreads();
    for (int off = 1; off < SCAN_NT; off <<= 1) {
        int v = (tid >= off) ? ps[tid - off] : 0;
        __syncthreads();
        ps[tid] += v;
        __syncthreads();
    }
    int run = (tid > 0) ? ps[tid - 1] : 0;
    for (int i = 0; i < CH; ++i) {
        int idx = tid * CH + i;
        if (idx < N_NODES) { base[idx] = run; run += cnt[idx]; }
    }
    if (tid == SCAN_NT - 1) base[N_NODES] = ps[SCAN_NT - 1];
}

__global__ void scatter_kernel(const int* __restrict__ ei, const int* __restrict__ base,
                               int* __restrict__ cnt2, int* __restrict__ srt)
{
    int e = blockIdx.x * 256 + threadIdx.x;
    if (e < N_EDGES) {
        int dst = ei[N_EDGES + e];
        int src = ei[e];
        if (dst >= 0 && dst < N_NODES) {
            int pos = base[dst] + atomicAdd(&cnt2[dst], 1);
            srt[pos] = src;
        }
    }
}

// ---------------- GATv2 aggregate: one wave per dst, online softmax, 2-edge pipeline ----------------
__global__ __launch_bounds__(256) void gat_kernel(
    const unsigned short* __restrict__ xl, const unsigned short* __restrict__ xr,
    const float* __restrict__ att, const float* __restrict__ gbias,
    const float* __restrict__ Wp, const float* __restrict__ bp,
    const int* __restrict__ base, const int* __restrict__ srt,
    float* __restrict__ out)
{
    const int wave = threadIdx.x >> 6;
    const int lane = threadIdx.x & 63;
    const int dst = blockIdx.x * 4 + wave;
    if (dst >= N_NODES) return;

    ushort8 xr8 = *(const ushort8*)&xr[(size_t)dst * G4 + lane * 8];
    float xrv[8];
#pragma unroll
    for (int i = 0; i < 8; ++i) xrv[i] = bf2f(xr8[i]);
    float4 at0 = *(const float4*)&att[lane * 8];
    float4 at1 = *(const float4*)&att[lane * 8 + 4];
    float atv[8] = {at0.x, at0.y, at0.z, at0.w, at1.x, at1.y, at1.z, at1.w};

    float m = -INFINITY, d = 0.0f;
    float acc[8];
#pragma unroll
    for (int i = 0; i < 8; ++i) acc[i] = 0.0f;

    const int b0 = base[dst], b1 = base[dst + 1];
    const int nE = b1 - b0 + 1;          // in-edges + self loop (last entry)
    int e = 0;
    // pair loop: both gathers issue before consumption; one softmax rescale per pair
    for (; e + 2 <= nE; e += 2) {
        int srcA = srt[b0 + e];                                    // e <= nE-2 -> always a real edge
        int srcB = (e + 1 == nE - 1) ? dst : srt[b0 + e + 1];
        ushort8 vA = *(const ushort8*)&xl[(size_t)srcA * G4 + lane * 8];
        ushort8 vB = *(const ushort8*)&xl[(size_t)srcB * G4 + lane * 8];
        float xvA[8], xvB[8];
#pragma unroll
        for (int i = 0; i < 8; ++i) { xvA[i] = bf2f(vA[i]); xvB[i] = bf2f(vB[i]); }
        float pA = 0.0f, pB = 0.0f;
#pragma unroll
        for (int i = 0; i < 8; ++i) {
            float eA = xvA[i] + xrv[i];
            float eB = xvB[i] + xrv[i];
            eA = (eA > 0.0f) ? eA : 0.2f * eA;
            eB = (eB > 0.0f) ? eB : 0.2f * eB;
            pA = fmaf(atv[i], eA, pA);
            pB = fmaf(atv[i], eB, pB);
        }
        pA += __shfl_xor(pA, 1); pB += __shfl_xor(pB, 1);
        pA += __shfl_xor(pA, 2); pB += __shfl_xor(pB, 2);
        pA += __shfl_xor(pA, 4); pB += __shfl_xor(pB, 4);
        pA += __shfl_xor(pA, 8); pB += __shfl_xor(pB, 8);
        float mn = fmaxf(m, fmaxf(pA, pB));
        float scale = __expf(m - mn);
        float alA = __expf(pA - mn);
        float alB = __expf(pB - mn);
        d = fmaf(d, scale, alA + alB);
#pragma unroll
        for (int i = 0; i < 8; ++i)
            acc[i] = fmaf(alB, xvB[i], fmaf(alA, xvA[i], acc[i] * scale));
        m = mn;
    }
    if (e < nE) {                        // leftover single entry (possibly the self loop)
        int src = (e == nE - 1) ? dst : srt[b0 + e];
        ushort8 v8 = *(const ushort8*)&xl[(size_t)src * G4 + lane * 8];
        float xv[8];
#pragma unroll
        for (int i = 0; i < 8; ++i) xv[i] = bf2f(v8[i]);
        float p = 0.0f;
#pragma unroll
        for (int i = 0; i < 8; ++i) {
            float ee = xv[i] + xrv[i];
            ee = (ee > 0.0f) ? ee : 0.2f * ee;
            p = fmaf(atv[i], ee, p);
        }
        p += __shfl_xor(p, 1);
        p += __shfl_xor(p, 2);
        p += __shfl_xor(p, 4);
        p += __shfl_xor(p, 8);
        float mn = fmaxf(m, p);
        float scale = __expf(m - mn);
        float al = __expf(p - mn);
        d = fmaf(d, scale, al);
#pragma unroll
        for (int i = 0; i < 8; ++i) acc[i] = fmaf(al, xv[i], acc[i] * scale);
        m = mn;
    }

    float inv = 1.0f / d;
    float o[8];
#pragma unroll
    for (int i = 0; i < 8; ++i) o[i] = acc[i] * inv;
#pragma unroll
    for (int i = 0; i < 8; ++i) {
        o[i] += __shfl_xor(o[i], 16);
        o[i] += __shfl_xor(o[i], 32);
    }
    const int c0 = (lane & 15) * 8;
    float psum = 0.0f;
#pragma unroll
    for (int i = 0; i < 8; ++i) {
        float s = 0.25f * o[i] + gbias[c0 + i];
        s = (s > 0.0f) ? s : (__expf(s) - 1.0f);
        psum = fmaf(s, Wp[c0 + i], psum);
    }
    psum += __shfl_xor(psum, 1);
    psum += __shfl_xor(psum, 2);
    psum += __shfl_xor(psum, 4);
    psum += __shfl_xor(psum, 8);
    if (lane == 0) out[dst] = psum + bp[0];
}

// ---------------- launch ----------------
extern "C" void kernel_launch(void* const* d_in, const int* in_sizes, int n_in,
                              void* d_out, int out_size, void* d_ws, size_t ws_size,
                              hipStream_t stream)
{
    const float* x        = (const float*)d_in[0];
    const int* ei         = (const int*)d_in[1];     // int32 per harness contract
    const float* Wih      = (const float*)d_in[2];
    const float* Whh      = (const float*)d_in[3];
    const float* bih      = (const float*)d_in[4];
    const float* bhh      = (const float*)d_in[5];
    const float* Wl       = (const float*)d_in[6];
    const float* bl       = (const float*)d_in[7];
    const float* Wr       = (const float*)d_in[8];
    const float* br       = (const float*)d_in[9];
    const float* att      = (const float*)d_in[10];
    const float* gbias    = (const float*)d_in[11];
    const float* Wp       = (const float*)d_in[12];
    const float* bp       = (const float*)d_in[13];
    float* out            = (float*)d_out;

    float* ws             = (float*)d_ws;
    unsigned short* wpk   = (unsigned short*)(ws + WPK_OFF);
    float* bsc            = ws + BIASC_OFF;
    unsigned short* wpk2  = (unsigned short*)(ws + WPK2_OFF);
    float* bsc2           = ws + BIASC2_OFF;
    unsigned short* h     = (unsigned short*)(ws + H_OFF);
    unsigned short* xlb   = (unsigned short*)(ws + XL_OFF);
    unsigned short* xrb   = (unsigned short*)(ws + XR_OFF);
    int* cnt    = (int*)(ws + CNT_OFF);
    int* cnt2   = (int*)(ws + CNT2_OFF);
    int* base   = (int*)(ws + BASE_OFF);
    int* srt    = (int*)(ws + SRT_OFF);

    hipMemsetAsync(cnt, 0, 2 * N_NODES * sizeof(int), stream);

    pack_w_kernel<<<320, 256, 0, stream>>>(Wih, Whh, bih, bhh, wpk, bsc);
    pack_w2_kernel<<<512, 256, 0, stream>>>(Wl, bl, Wr, br, wpk2, bsc2);
    count_kernel<<<(N_EDGES + 255) / 256, 256, 0, stream>>>(ei, cnt);
    scan_kernel<<<1, SCAN_NT, 0, stream>>>(cnt, base);
    scatter_kernel<<<(N_EDGES + 255) / 256, 256, 0, stream>>>(ei, base, cnt2, srt);

    lstm_mfma_kernel<<<N_NODES / BMM, 512, 0, stream>>>(x, wpk, bsc, h);
    gemm2_mfma_kernel<<<((N_NODES + G2_BM - 1) / G2_BM) * 4, 256, 0, stream>>>(h, wpk2, bsc2, xlb, xrb);
    gat_kernel<<<(N_NODES + 3) / 4, 256, 0, stream>>>(xlb, xrb, att, gbias, Wp, bp, base, srt, out);
}

// Round 14
// 366.221 us; speedup vs baseline: 2.5394x; 1.0739x over previous
//
#include <hip/hip_runtime.h>
#include <hip/hip_bf16.h>

#define N_NODES 20000
#define N_EDGES 250000
#define T_WIN   60
#define F_IN    16
#define HID     128
#define G4      512      // 4*HID
#define HEADS   4

// ---------------- ws layout (float offsets) ----------------
#define WPK_OFF    0            // 81920 ushort (LSTM W B-frags)
#define BIASC_OFF  40960        // 512
#define WPK2_OFF   41472        // 131072 ushort (GAT-lin W B-frags) = 65536 floats
#define BIASC2_OFF 107008       // 1024
#define H_OFF      108032       // 20000*128 ushort (bf16 h) = 1,280,000 floats
#define XL_OFF     1388032      // 20000*512 ushort = 5,120,000 floats
#define XR_OFF     6508032      // 20000*512 ushort
#define CNT_OFF    11628032     // 20000 ints
#define CNT2_OFF   11648032     // 20000 ints
#define BASE_OFF   11668032     // 20001 ints
#define SRT_OFF    11688033     // 250000 ints

typedef __attribute__((ext_vector_type(8))) short short8;
typedef __attribute__((ext_vector_type(8))) unsigned short ushort8;
typedef __attribute__((ext_vector_type(4))) float f32x4;
typedef __attribute__((ext_vector_type(4))) unsigned short ushortx4;

#define LOG2E   1.442695041f
#define LOG2E2  2.885390082f

// compiler-known transcendentals ONLY (r7 lesson: inline-asm v_exp_f32 defeats the
// trans-op hazard recognizer -> stale-register reads -> 6.8e-2 corruption).
__device__ __forceinline__ float fexp2(float x) { return __builtin_amdgcn_exp2f(x); }
__device__ __forceinline__ float frcp(float x)  { return __builtin_amdgcn_rcpf(x); }

__device__ __forceinline__ unsigned short f2bf(float f) {
    unsigned u = __float_as_uint(f);
    u += 0x7FFFu + ((u >> 16) & 1u);   // RNE
    return (unsigned short)(u >> 16);
}
__device__ __forceinline__ float bf2f(unsigned short u) {
    return __uint_as_float((unsigned)u << 16);
}
__device__ __forceinline__ unsigned cvt_pk_bf16(float a, float b) {
    unsigned r;
    asm("v_cvt_pk_bf16_f32 %0, %1, %2" : "=v"(r) : "v"(a), "v"(b));
    return r;
}

// ---------------- pack LSTM W into MFMA B-fragment layout, exp2-prescaled ----------------
// Wpk index = (((g*8+ht)*5+kt)*64 + lane)*8 + i
// element: k = kt*32 + (lane>>4)*8 + i ; col = g*128 + ht*16 + (lane&15)
// gates i,f,o scaled by -log2(e); gate g (idx 2) by -2log2(e):
//   sigmoid(x) = rcp(1 + exp2(-log2e*x)) ; tanh(x) = 2*rcp(1 + exp2(-2log2e*x)) - 1
__global__ void pack_w_kernel(const float* __restrict__ Wih, const float* __restrict__ Whh,
                              const float* __restrict__ bih, const float* __restrict__ bhh,
                              unsigned short* __restrict__ wpk, float* __restrict__ biasc)
{
    int idx = blockIdx.x * 256 + threadIdx.x;
    if (idx < 81920) {
        int i  = idx & 7;
        int l  = (idx >> 3) & 63;
        int r  = idx >> 9;
        int kt = r % 5;
        int gh = r / 5;
        int ht = gh & 7;
        int g  = gh >> 3;
        int k   = kt * 32 + (l >> 4) * 8 + i;
        int col = g * 128 + ht * 16 + (l & 15);
        float v = 0.0f;
        if (k < 128)      v = Whh[col * 128 + k];
        else if (k < 144) v = Wih[col * 16 + (k - 128)];
        float sc = (g == 2) ? -LOG2E2 : -LOG2E;
        wpk[idx] = f2bf(v * sc);
    }
    if (idx < G4) {
        int g = idx >> 7;
        float sc = (g == 2) ? -LOG2E2 : -LOG2E;
        biasc[idx] = (bih[idx] + bhh[idx]) * sc;
    }
}

// ---------------- pack GAT lin W (Wl|Wr -> [128 k][1024 cols]) into B-frags ----------------
__global__ void pack_w2_kernel(const float* __restrict__ Wl, const float* __restrict__ bl,
                               const float* __restrict__ Wr, const float* __restrict__ br,
                               unsigned short* __restrict__ wpk2, float* __restrict__ biasc2)
{
    int idx = blockIdx.x * 256 + threadIdx.x;
    if (idx < 131072) {
        int i  = idx & 7;
        int l  = (idx >> 3) & 63;
        int f  = idx >> 9;       // ht*4 + kt
        int kt = f & 3;
        int ht = f >> 2;
        int k   = kt * 32 + (l >> 4) * 8 + i;
        int col = ht * 16 + (l & 15);
        float v = (col < 512) ? Wl[col * 128 + k] : Wr[(col - 512) * 128 + k];
        wpk2[idx] = f2bf(v);
    }
    if (idx < 1024) biasc2[idx] = (idx < 512) ? bl[idx] : br[idx - 512];
}

// ---------------- LSTM: MFMA bf16, 80 nodes/block, 250 blocks (r13 base, 296 us) ----------------
// OCCUPANCY VERDICT (r8-r12): 512-thread blocks never co-schedule 2/CU; 1024-thread
// blocks hard-cap at 64 VGPR (all annotations no-ops) -> spill. 8 waves @ 512 thr,
// 1 block/CU, VGPR ~120 is the local optimum. Time loop unroll 1 ON PURPOSE (r4 spill).
// r14 deltas: bias as MFMA C-in (bit-exact, -80 movs/step); exp2-prescaled weights
// (-100 muls/step); precomputed LDS h-write offsets (-~120 addr ops/step).
#define BMM  80
#define ASTR 384
#define PANEL (BMM * ASTR)

__global__ __launch_bounds__(512) void lstm_mfma_kernel(
    const float* __restrict__ x, const unsigned short* __restrict__ wpk,
    const float* __restrict__ biasc, unsigned short* __restrict__ hout)
{
    __shared__ __align__(16) unsigned char Abuf[2][PANEL];
    const int tid  = threadIdx.x;
    const int wave = tid >> 6;
    const int lane = tid & 63;
    const int n0   = blockIdx.x * BMM;

    {
        f32x4 z = {0.0f, 0.0f, 0.0f, 0.0f};
        unsigned char* ab = &Abuf[0][0];
        for (int i = tid; i < 2 * PANEL / 16; i += 512)
            *(f32x4*)&ab[i * 16] = z;
    }

    // persistent B-fragments: wave w owns hid cols [w*16, w*16+16) for all 4 gates
    short8 wf[4][5];
#pragma unroll
    for (int g = 0; g < 4; ++g)
#pragma unroll
        for (int kt = 0; kt < 5; ++kt)
            wf[g][kt] = *(const short8*)&wpk[((((g * 8 + wave) * 5) + kt) * 64 + lane) * 8];

    // bias as MFMA C-in (prescaled at pack time)
    f32x4 bias_c[4];
#pragma unroll
    for (int g = 0; g < 4; ++g) {
        float b = biasc[g * 128 + wave * 16 + (lane & 15)];
        f32x4 a = {b, b, b, b};
        bias_c[g] = a;
    }

    float c[5][4];
#pragma unroll
    for (int mt = 0; mt < 5; ++mt)
#pragma unroll
        for (int r = 0; r < 4; ++r) c[mt][r] = 0.0f;

    const int  xnode   = tid >> 2;
    const int  xq      = tid & 3;
    const bool xactive = (tid < BMM * 4);
    const int  xoff    = (256 + xq * 8) ^ ((xnode & 7) << 4);
    const int  colw    = wave * 16 + (lane & 15);
    const float* xptr  = &x[(size_t)(n0 + xnode) * (T_WIN * F_IN) + xq * 4];

    // precomputed h-write LDS offsets: node = mt*16 + nd, swizzle depends on nd&7 only
    // (mt*16 ≡ 0 mod 8), so offsets are mt-invariant up to + mt*16*ASTR.
    unsigned wroff[2][2];
#pragma unroll
    for (int rp = 0; rp < 2; ++rp)
#pragma unroll
        for (int w = 0; w < 2; ++w) {
            int nd = (lane >> 4) * 4 + rp * 2 + w;
            wroff[rp][w] = nd * ASTR + ((colw * 2) ^ ((nd & 7) << 4));
        }

    __syncthreads();

    if (xactive) {
        float4 v = *(const float4*)xptr;
        ushortx4 b;
        b.x = f2bf(v.x); b.y = f2bf(v.y); b.z = f2bf(v.z); b.w = f2bf(v.w);
        *(ushortx4*)&Abuf[0][xnode * ASTR + xoff] = b;
    }
    __syncthreads();

#pragma unroll 1
    for (int t = 0; t < T_WIN; ++t) {
        const int cur = t & 1;
        const int nxt = cur ^ 1;
        unsigned char* pnxt = &Abuf[nxt][0];

        float4 xv = {0.0f, 0.0f, 0.0f, 0.0f};
        if (xactive && t + 1 < T_WIN) xv = *(const float4*)(xptr + (t + 1) * F_IN);

        // per-mt: ds_read -> 20 MFMA -> activation (act(mt) overlaps MFMA(mt+1))
#pragma unroll
        for (int mt = 0; mt < 5; ++mt) {
            const int row = mt * 16 + (lane & 15);
            const int rsw = (row & 7) << 4;
            short8 af[5];
#pragma unroll
            for (int kt = 0; kt < 5; ++kt)
                af[kt] = *(const short8*)&Abuf[cur][row * ASTR + ((kt * 64 + (lane >> 4) * 16) ^ rsw)];

            f32x4 ag[4];
#pragma unroll
            for (int g = 0; g < 4; ++g)
                ag[g] = __builtin_amdgcn_mfma_f32_16x16x32_bf16(af[0], wf[g][0], bias_c[g], 0, 0, 0);
#pragma unroll
            for (int kt = 1; kt < 5; ++kt)
#pragma unroll
                for (int g = 0; g < 4; ++g)
                    ag[g] = __builtin_amdgcn_mfma_f32_16x16x32_bf16(af[kt], wf[g][kt], ag[g], 0, 0, 0);

#pragma unroll
            for (int rp = 0; rp < 2; ++rp) {
                float hh[2];
#pragma unroll
                for (int r2 = 0; r2 < 2; ++r2) {
                    const int r = rp * 2 + r2;
                    float si = frcp(1.0f + fexp2(ag[0][r]));                     // sigmoid(i)
                    float sf = frcp(1.0f + fexp2(ag[1][r]));                     // sigmoid(f)
                    float gg = fmaf(2.0f, frcp(1.0f + fexp2(ag[2][r])), -1.0f);  // tanh(g)
                    float so = frcp(1.0f + fexp2(ag[3][r]));                     // sigmoid(o)
                    float cn = fmaf(sf, c[mt][r], si * gg);
                    c[mt][r] = cn;
                    float th = fmaf(2.0f, frcp(1.0f + fexp2(-LOG2E2 * cn)), -1.0f);
                    hh[r2] = so * th;
                }
                const unsigned pk = cvt_pk_bf16(hh[0], hh[1]);
                if (t < T_WIN - 1) {
                    *(unsigned short*)(pnxt + mt * (16 * ASTR) + wroff[rp][0]) = (unsigned short)pk;
                    *(unsigned short*)(pnxt + mt * (16 * ASTR) + wroff[rp][1]) = (unsigned short)(pk >> 16);
                } else {
                    const int node0 = mt * 16 + (lane >> 4) * 4 + rp * 2;
                    hout[(size_t)(n0 + node0) * HID + colw]     = (unsigned short)pk;
                    hout[(size_t)(n0 + node0 + 1) * HID + colw] = (unsigned short)(pk >> 16);
                }
            }
        }

        if (xactive && t + 1 < T_WIN) {
            ushortx4 b;
            b.x = f2bf(xv.x); b.y = f2bf(xv.y); b.z = f2bf(xv.z); b.w = f2bf(xv.w);
            *(ushortx4*)(pnxt + xnode * ASTR + xoff) = b;
        }
        __syncthreads();
    }
}

// ---------------- GEMM2 (MFMA): [xl|xr] = h @ [Wl|Wr]^T + bias, bf16 in/out ----------------
#define G2_BM 64
__global__ __launch_bounds__(256) void gemm2_mfma_kernel(
    const unsigned short* __restrict__ hbf,   // [20000][128] bf16
    const unsigned short* __restrict__ wpk2,  // packed B-frags
    const float* __restrict__ biasc2,         // [1024]
    unsigned short* __restrict__ xl, unsigned short* __restrict__ xr)
{
    __shared__ __align__(16) unsigned char Hs[G2_BM * 256];  // [64 rows][128 bf16], XOR-swizzled
    const int tid  = threadIdx.x;
    const int wave = tid >> 6;
    const int lane = tid & 63;
    const int mb = blockIdx.x >> 2;
    const int nb = blockIdx.x & 3;     // 4 col-blocks of 256 (0,1 -> xl; 2,3 -> xr)
    const int n0 = mb * G2_BM;

#pragma unroll
    for (int q = 0; q < 4; ++q) {
        int fi = tid + q * 256;
        int node = fi >> 4;
        int kb = (fi & 15) * 16;
        ushort8 v = {0, 0, 0, 0, 0, 0, 0, 0};
        if (n0 + node < N_NODES) v = *(const ushort8*)&hbf[(size_t)(n0 + node) * HID + kb / 2];
        *(ushort8*)&Hs[node * 256 + (kb ^ ((node & 7) << 4))] = v;
    }
    __syncthreads();

    const int colt0 = nb * 16 + wave * 4;
    float bias4[4];
#pragma unroll
    for (int ct = 0; ct < 4; ++ct)
        bias4[ct] = biasc2[(colt0 + ct) * 16 + (lane & 15)];

    f32x4 acc[4][4];
#pragma unroll
    for (int mt = 0; mt < 4; ++mt)
#pragma unroll
        for (int ct = 0; ct < 4; ++ct) {
            f32x4 a = {bias4[ct], bias4[ct], bias4[ct], bias4[ct]};
            acc[mt][ct] = a;
        }

#pragma unroll
    for (int kt = 0; kt < 4; ++kt) {
        short8 wf[4];
#pragma unroll
        for (int ct = 0; ct < 4; ++ct)
            wf[ct] = *(const short8*)&wpk2[(((colt0 + ct) * 4 + kt) * 64 + lane) * 8];
        short8 af[4];
        const int kbyte = kt * 64 + (lane >> 4) * 16;
#pragma unroll
        for (int mt = 0; mt < 4; ++mt) {
            int row = mt * 16 + (lane & 15);
            af[mt] = *(const short8*)&Hs[row * 256 + (kbyte ^ ((row & 7) << 4))];
        }
#pragma unroll
        for (int mt = 0; mt < 4; ++mt)
#pragma unroll
            for (int ct = 0; ct < 4; ++ct)
                acc[mt][ct] = __builtin_amdgcn_mfma_f32_16x16x32_bf16(af[mt], wf[ct], acc[mt][ct], 0, 0, 0);
    }

    unsigned short* outp = (nb < 2) ? xl : xr;
    const int lcol = (nb & 1) * 256 + wave * 64 + (lane & 15);
#pragma unroll
    for (int mt = 0; mt < 4; ++mt)
#pragma unroll
        for (int ct = 0; ct < 4; ++ct)
#pragma unroll
            for (int r = 0; r < 4; ++r) {
                int row = n0 + mt * 16 + (lane >> 4) * 4 + r;
                if (row < N_NODES)
                    outp[(size_t)row * G4 + lcol + ct * 16] = f2bf(acc[mt][ct][r]);
            }
}

// ---------------- edge sort (counting sort by dst) ----------------
__global__ void count_kernel(const int* __restrict__ ei, int* __restrict__ cnt)
{
    int e = blockIdx.x * 256 + threadIdx.x;
    if (e < N_EDGES) {
        int dst = ei[N_EDGES + e];
        if (dst >= 0 && dst < N_NODES) atomicAdd(&cnt[dst], 1);
    }
}

#define SCAN_NT 1024
__global__ __launch_bounds__(SCAN_NT) void scan_kernel(const int* __restrict__ cnt, int* __restrict__ base)
{
    __shared__ int ps[SCAN_NT];
    const int tid = threadIdx.x;
    const int CH = (N_NODES + SCAN_NT - 1) / SCAN_NT;  // 20
    int s = 0;
    for (int i = 0; i < CH; ++i) {
        int idx = tid * CH + i;
        if (idx < N_NODES) s += cnt[idx];
    }
    ps[tid] = s;
    __syncthreads();
    for (int off = 1; off < SCAN_NT; off <<= 1) {
        int v = (tid >= off) ? ps[tid - off] : 0;
        __syncthreads();
        ps[tid] += v;
        __syncthreads();
    }
    int run = (tid > 0) ? ps[tid - 1] : 0;
    for (int i = 0; i < CH; ++i) {
        int idx = tid * CH + i;
        if (idx < N_NODES) { base[idx] = run; run += cnt[idx]; }
    }
    if (tid == SCAN_NT - 1) base[N_NODES] = ps[SCAN_NT - 1];
}

__global__ void scatter_kernel(const int* __restrict__ ei, const int* __restrict__ base,
                               int* __restrict__ cnt2, int* __restrict__ srt)
{
    int e = blockIdx.x * 256 + threadIdx.x;
    if (e < N_EDGES) {
        int dst = ei[N_EDGES + e];
        int src = ei[e];
        if (dst >= 0 && dst < N_NODES) {
            int pos = base[dst] + atomicAdd(&cnt2[dst], 1);
            srt[pos] = src;
        }
    }
}

// ---------------- GATv2 aggregate: one wave per dst, online softmax, 2-edge pipeline ----------------
__global__ __launch_bounds__(256) void gat_kernel(
    const unsigned short* __restrict__ xl, const unsigned short* __restrict__ xr,
    const float* __restrict__ att, const float* __restrict__ gbias,
    const float* __restrict__ Wp, const float* __restrict__ bp,
    const int* __restrict__ base, const int* __restrict__ srt,
    float* __restrict__ out)
{
    const int wave = threadIdx.x >> 6;
    const int lane = threadIdx.x & 63;
    const int dst = blockIdx.x * 4 + wave;
    if (dst >= N_NODES) return;

    ushort8 xr8 = *(const ushort8*)&xr[(size_t)dst * G4 + lane * 8];
    float xrv[8];
#pragma unroll
    for (int i = 0; i < 8; ++i) xrv[i] = bf2f(xr8[i]);
    float4 at0 = *(const float4*)&att[lane * 8];
    float4 at1 = *(const float4*)&att[lane * 8 + 4];
    float atv[8] = {at0.x, at0.y, at0.z, at0.w, at1.x, at1.y, at1.z, at1.w};

    float m = -INFINITY, d = 0.0f;
    float acc[8];
#pragma unroll
    for (int i = 0; i < 8; ++i) acc[i] = 0.0f;

    const int b0 = base[dst], b1 = base[dst + 1];
    const int nE = b1 - b0 + 1;          // in-edges + self loop (last entry)
    int e = 0;
    // pair loop: both gathers issue before consumption; one softmax rescale per pair
    for (; e + 2 <= nE; e += 2) {
        int srcA = srt[b0 + e];                                    // e <= nE-2 -> always a real edge
        int srcB = (e + 1 == nE - 1) ? dst : srt[b0 + e + 1];
        ushort8 vA = *(const ushort8*)&xl[(size_t)srcA * G4 + lane * 8];
        ushort8 vB = *(const ushort8*)&xl[(size_t)srcB * G4 + lane * 8];
        float xvA[8], xvB[8];
#pragma unroll
        for (int i = 0; i < 8; ++i) { xvA[i] = bf2f(vA[i]); xvB[i] = bf2f(vB[i]); }
        float pA = 0.0f, pB = 0.0f;
#pragma unroll
        for (int i = 0; i < 8; ++i) {
            float eA = xvA[i] + xrv[i];
            float eB = xvB[i] + xrv[i];
            eA = (eA > 0.0f) ? eA : 0.2f * eA;
            eB = (eB > 0.0f) ? eB : 0.2f * eB;
            pA = fmaf(atv[i], eA, pA);
            pB = fmaf(atv[i], eB, pB);
        }
        pA += __shfl_xor(pA, 1); pB += __shfl_xor(pB, 1);
        pA += __shfl_xor(pA, 2); pB += __shfl_xor(pB, 2);
        pA += __shfl_xor(pA, 4); pB += __shfl_xor(pB, 4);
        pA += __shfl_xor(pA, 8); pB += __shfl_xor(pB, 8);
        float mn = fmaxf(m, fmaxf(pA, pB));
        float scale = __expf(m - mn);
        float alA = __expf(pA - mn);
        float alB = __expf(pB - mn);
        d = fmaf(d, scale, alA + alB);
#pragma unroll
        for (int i = 0; i < 8; ++i)
            acc[i] = fmaf(alB, xvB[i], fmaf(alA, xvA[i], acc[i] * scale));
        m = mn;
    }
    if (e < nE) {                        // leftover single entry (possibly the self loop)
        int src = (e == nE - 1) ? dst : srt[b0 + e];
        ushort8 v8 = *(const ushort8*)&xl[(size_t)src * G4 + lane * 8];
        float xv[8];
#pragma unroll
        for (int i = 0; i < 8; ++i) xv[i] = bf2f(v8[i]);
        float p = 0.0f;
#pragma unroll
        for (int i = 0; i < 8; ++i) {
            float ee = xv[i] + xrv[i];
            ee = (ee > 0.0f) ? ee : 0.2f * ee;
            p = fmaf(atv[i], ee, p);
        }
        p += __shfl_xor(p, 1);
        p += __shfl_xor(p, 2);
        p += __shfl_xor(p, 4);
        p += __shfl_xor(p, 8);
        float mn = fmaxf(m, p);
        float scale = __expf(m - mn);
        float al = __expf(p - mn);
        d = fmaf(d, scale, al);
#pragma unroll
        for (int i = 0; i < 8; ++i) acc[i] = fmaf(al, xv[i], acc[i] * scale);
        m = mn;
    }

    float inv = 1.0f / d;
    float o[8];
#pragma unroll
    for (int i = 0; i < 8; ++i) o[i] = acc[i] * inv;
#pragma unroll
    for (int i = 0; i < 8; ++i) {
        o[i] += __shfl_xor(o[i], 16);
        o[i] += __shfl_xor(o[i], 32);
    }
    const int c0 = (lane & 15) * 8;
    float psum = 0.0f;
#pragma unroll
    for (int i = 0; i < 8; ++i) {
        float s = 0.25f * o[i] + gbias[c0 + i];
        s = (s > 0.0f) ? s : (__expf(s) - 1.0f);
        psum = fmaf(s, Wp[c0 + i], psum);
    }
    psum += __shfl_xor(psum, 1);
    psum += __shfl_xor(psum, 2);
    psum += __shfl_xor(psum, 4);
    psum += __shfl_xor(psum, 8);
    if (lane == 0) out[dst] = psum + bp[0];
}

// ---------------- launch ----------------
extern "C" void kernel_launch(void* const* d_in, const int* in_sizes, int n_in,
                              void* d_out, int out_size, void* d_ws, size_t ws_size,
                              hipStream_t stream)
{
    const float* x        = (const float*)d_in[0];
    const int* ei         = (const int*)d_in[1];     // int32 per harness contract
    const float* Wih      = (const float*)d_in[2];
    const float* Whh      = (const float*)d_in[3];
    const float* bih      = (const float*)d_in[4];
    const float* bhh      = (const float*)d_in[5];
    const float* Wl       = (const float*)d_in[6];
    const float* bl       = (const float*)d_in[7];
    const float* Wr       = (const float*)d_in[8];
    const float* br       = (const float*)d_in[9];
    const float* att      = (const float*)d_in[10];
    const float* gbias    = (const float*)d_in[11];
    const float* Wp       = (const float*)d_in[12];
    const float* bp       = (const float*)d_in[13];
    float* out            = (float*)d_out;

    float* ws             = (float*)d_ws;
    unsigned short* wpk   = (unsigned short*)(ws + WPK_OFF);
    float* bsc            = ws + BIASC_OFF;
    unsigned short* wpk2  = (unsigned short*)(ws + WPK2_OFF);
    float* bsc2           = ws + BIASC2_OFF;
    unsigned short* h     = (unsigned short*)(ws + H_OFF);
    unsigned short* xlb   = (unsigned short*)(ws + XL_OFF);
    unsigned short* xrb   = (unsigned short*)(ws + XR_OFF);
    int* cnt    = (int*)(ws + CNT_OFF);
    int* cnt2   = (int*)(ws + CNT2_OFF);
    int* base   = (int*)(ws + BASE_OFF);
    int* srt    = (int*)(ws + SRT_OFF);

    hipMemsetAsync(cnt, 0, 2 * N_NODES * sizeof(int), stream);

    pack_w_kernel<<<320, 256, 0, stream>>>(Wih, Whh, bih, bhh, wpk, bsc);
    pack_w2_kernel<<<512, 256, 0, stream>>>(Wl, bl, Wr, br, wpk2, bsc2);
    count_kernel<<<(N_EDGES + 255) / 256, 256, 0, stream>>>(ei, cnt);
    scan_kernel<<<1, SCAN_NT, 0, stream>>>(cnt, base);
    scatter_kernel<<<(N_EDGES + 255) / 256, 256, 0, stream>>>(ei, base, cnt2, srt);

    lstm_mfma_kernel<<<N_NODES / BMM, 512, 0, stream>>>(x, wpk, bsc, h);
    gemm2_mfma_kernel<<<((N_NODES + G2_BM - 1) / G2_BM) * 4, 256, 0, stream>>>(h, wpk2, bsc2, xlb, xrb);
    gat_kernel<<<(N_NODES + 3) / 4, 256, 0, stream>>>(xlb, xrb, att, gbias, Wp, bp, base, srt, out);
}

// Round 15
// 349.804 us; speedup vs baseline: 2.6585x; 1.0469x over previous
//
#include <hip/hip_runtime.h>
#include <hip/hip_bf16.h>

#define N_NODES 20000
#define N_EDGES 250000
#define T_WIN   60
#define F_IN    16
#define HID     128
#define G4      512      // 4*HID
#define HEADS   4

// ---------------- ws layout (float offsets) ----------------
#define WPK_OFF    0            // 81920 ushort (LSTM W B-frags)
#define BIASC_OFF  40960        // 512
#define WPK2_OFF   41472        // 131072 ushort (GAT-lin W B-frags) = 65536 floats
#define BIASC2_OFF 107008       // 1024
#define H_OFF      108032       // 20000*128 ushort (bf16 h) = 1,280,000 floats
#define XL_OFF     1388032      // 20000*512 ushort = 5,120,000 floats
#define XR_OFF     6508032      // 20000*512 ushort
#define CNT_OFF    11628032     // 20000 ints
#define CNT2_OFF   11648032     // 20000 ints
#define BASE_OFF   11668032     // 20001 ints
#define SRT_OFF    11688033     // 250000 ints

typedef __attribute__((ext_vector_type(8))) short short8;
typedef __attribute__((ext_vector_type(8))) unsigned short ushort8;
typedef __attribute__((ext_vector_type(4))) float f32x4;
typedef __attribute__((ext_vector_type(4))) unsigned short ushortx4;

#define LOG2E   1.442695041f
#define LOG2E2  2.885390082f

// compiler-known transcendentals ONLY (r7 lesson: inline-asm v_exp_f32 defeats the
// trans-op hazard recognizer -> stale-register reads -> 6.8e-2 corruption).
__device__ __forceinline__ float fexp2(float x) { return __builtin_amdgcn_exp2f(x); }
__device__ __forceinline__ float frcp(float x)  { return __builtin_amdgcn_rcpf(x); }

__device__ __forceinline__ unsigned short f2bf(float f) {
    unsigned u = __float_as_uint(f);
    u += 0x7FFFu + ((u >> 16) & 1u);   // RNE
    return (unsigned short)(u >> 16);
}
__device__ __forceinline__ float bf2f(unsigned short u) {
    return __uint_as_float((unsigned)u << 16);
}
__device__ __forceinline__ unsigned cvt_pk_bf16(float a, float b) {
    unsigned r;
    asm("v_cvt_pk_bf16_f32 %0, %1, %2" : "=v"(r) : "v"(a), "v"(b));
    return r;
}

// ---------------- pack LSTM W into MFMA B-fragment layout, exp2-prescaled ----------------
// Wpk index = (((g*8+ht)*5+kt)*64 + lane)*8 + i
// element: k = kt*32 + (lane>>4)*8 + i ; col = g*128 + ht*16 + (lane&15)
// gates i,f,o scaled by -log2(e); gate g (idx 2) by -2log2(e):
//   sigmoid(x) = rcp(1 + exp2(-log2e*x)) ; tanh(x) = (1-b)/(1+b), b = exp2(-2log2e*x)
__global__ void pack_w_kernel(const float* __restrict__ Wih, const float* __restrict__ Whh,
                              const float* __restrict__ bih, const float* __restrict__ bhh,
                              unsigned short* __restrict__ wpk, float* __restrict__ biasc)
{
    int idx = blockIdx.x * 256 + threadIdx.x;
    if (idx < 81920) {
        int i  = idx & 7;
        int l  = (idx >> 3) & 63;
        int r  = idx >> 9;
        int kt = r % 5;
        int gh = r / 5;
        int ht = gh & 7;
        int g  = gh >> 3;
        int k   = kt * 32 + (l >> 4) * 8 + i;
        int col = g * 128 + ht * 16 + (l & 15);
        float v = 0.0f;
        if (k < 128)      v = Whh[col * 128 + k];
        else if (k < 144) v = Wih[col * 16 + (k - 128)];
        float sc = (g == 2) ? -LOG2E2 : -LOG2E;
        wpk[idx] = f2bf(v * sc);
    }
    if (idx < G4) {
        int g = idx >> 7;
        float sc = (g == 2) ? -LOG2E2 : -LOG2E;
        biasc[idx] = (bih[idx] + bhh[idx]) * sc;
    }
}

// ---------------- pack GAT lin W (Wl|Wr -> [128 k][1024 cols]) into B-frags ----------------
__global__ void pack_w2_kernel(const float* __restrict__ Wl, const float* __restrict__ bl,
                               const float* __restrict__ Wr, const float* __restrict__ br,
                               unsigned short* __restrict__ wpk2, float* __restrict__ biasc2)
{
    int idx = blockIdx.x * 256 + threadIdx.x;
    if (idx < 131072) {
        int i  = idx & 7;
        int l  = (idx >> 3) & 63;
        int f  = idx >> 9;       // ht*4 + kt
        int kt = f & 3;
        int ht = f >> 2;
        int k   = kt * 32 + (l >> 4) * 8 + i;
        int col = ht * 16 + (l & 15);
        float v = (col < 512) ? Wl[col * 128 + k] : Wr[(col - 512) * 128 + k];
        wpk2[idx] = f2bf(v);
    }
    if (idx < 1024) biasc2[idx] = (idx < 512) ? bl[idx] : br[idx - 512];
}

// ---------------- LSTM: MFMA bf16, 80 nodes/block, 250 blocks ----------------
// OCCUPANCY VERDICT (r8-r12): 512-thread blocks never co-schedule 2/CU; 1024-thread
// blocks hard-cap at 64 VGPR -> spill. 8 waves @ 512 thr, 1 block/CU is the optimum.
// Time loop unroll 1 ON PURPOSE (r4 spill). Bias as MFMA C-in; exp2-prescaled W;
// precomputed LDS h-write offsets. r15: fused-rcp activations (5 exp2 + 3 rcp/elem).
#define BMM  80
#define ASTR 384
#define PANEL (BMM * ASTR)

__global__ __launch_bounds__(512) void lstm_mfma_kernel(
    const float* __restrict__ x, const unsigned short* __restrict__ wpk,
    const float* __restrict__ biasc, unsigned short* __restrict__ hout)
{
    __shared__ __align__(16) unsigned char Abuf[2][PANEL];
    const int tid  = threadIdx.x;
    const int wave = tid >> 6;
    const int lane = tid & 63;
    const int n0   = blockIdx.x * BMM;

    {
        f32x4 z = {0.0f, 0.0f, 0.0f, 0.0f};
        unsigned char* ab = &Abuf[0][0];
        for (int i = tid; i < 2 * PANEL / 16; i += 512)
            *(f32x4*)&ab[i * 16] = z;
    }

    // persistent B-fragments: wave w owns hid cols [w*16, w*16+16) for all 4 gates
    short8 wf[4][5];
#pragma unroll
    for (int g = 0; g < 4; ++g)
#pragma unroll
        for (int kt = 0; kt < 5; ++kt)
            wf[g][kt] = *(const short8*)&wpk[((((g * 8 + wave) * 5) + kt) * 64 + lane) * 8];

    // bias as MFMA C-in (prescaled at pack time)
    f32x4 bias_c[4];
#pragma unroll
    for (int g = 0; g < 4; ++g) {
        float b = biasc[g * 128 + wave * 16 + (lane & 15)];
        f32x4 a = {b, b, b, b};
        bias_c[g] = a;
    }

    float c[5][4];
#pragma unroll
    for (int mt = 0; mt < 5; ++mt)
#pragma unroll
        for (int r = 0; r < 4; ++r) c[mt][r] = 0.0f;

    const int  xnode   = tid >> 2;
    const int  xq      = tid & 3;
    const bool xactive = (tid < BMM * 4);
    const int  xoff    = (256 + xq * 8) ^ ((xnode & 7) << 4);
    const int  colw    = wave * 16 + (lane & 15);
    const float* xptr  = &x[(size_t)(n0 + xnode) * (T_WIN * F_IN) + xq * 4];

    // precomputed h-write LDS offsets (mt*16 ≡ 0 mod 8 -> swizzle mt-invariant)
    unsigned wroff[2][2];
#pragma unroll
    for (int rp = 0; rp < 2; ++rp)
#pragma unroll
        for (int w = 0; w < 2; ++w) {
            int nd = (lane >> 4) * 4 + rp * 2 + w;
            wroff[rp][w] = nd * ASTR + ((colw * 2) ^ ((nd & 7) << 4));
        }

    __syncthreads();

    if (xactive) {
        float4 v = *(const float4*)xptr;
        ushortx4 b;
        b.x = f2bf(v.x); b.y = f2bf(v.y); b.z = f2bf(v.z); b.w = f2bf(v.w);
        *(ushortx4*)&Abuf[0][xnode * ASTR + xoff] = b;
    }
    __syncthreads();

#pragma unroll 1
    for (int t = 0; t < T_WIN; ++t) {
        const int cur = t & 1;
        const int nxt = cur ^ 1;
        unsigned char* pnxt = &Abuf[nxt][0];

        float4 xv = {0.0f, 0.0f, 0.0f, 0.0f};
        if (xactive && t + 1 < T_WIN) xv = *(const float4*)(xptr + (t + 1) * F_IN);

        // per-mt: ds_read -> 20 MFMA -> activation (act(mt) overlaps MFMA(mt+1))
#pragma unroll
        for (int mt = 0; mt < 5; ++mt) {
            const int row = mt * 16 + (lane & 15);
            const int rsw = (row & 7) << 4;
            short8 af[5];
#pragma unroll
            for (int kt = 0; kt < 5; ++kt)
                af[kt] = *(const short8*)&Abuf[cur][row * ASTR + ((kt * 64 + (lane >> 4) * 16) ^ rsw)];

            f32x4 ag[4];
#pragma unroll
            for (int g = 0; g < 4; ++g)
                ag[g] = __builtin_amdgcn_mfma_f32_16x16x32_bf16(af[0], wf[g][0], bias_c[g], 0, 0, 0);
#pragma unroll
            for (int kt = 1; kt < 5; ++kt)
#pragma unroll
                for (int g = 0; g < 4; ++g)
                    ag[g] = __builtin_amdgcn_mfma_f32_16x16x32_bf16(af[kt], wf[g][kt], ag[g], 0, 0, 0);

#pragma unroll
            for (int rp = 0; rp < 2; ++rp) {
                float hh[2];
#pragma unroll
                for (int r2 = 0; r2 < 2; ++r2) {
                    const int r = rp * 2 + r2;
                    // fused-rcp activations: a=e^-i, fv=e^-f, b=e^-2g, cc=e^-o, dd=e^-2cn
                    float a  = fexp2(ag[0][r]);
                    float fv = fexp2(ag[1][r]);
                    float b  = fexp2(ag[2][r]);
                    float cc = fexp2(ag[3][r]);
                    float sf = frcp(1.0f + fv);                                   // sigmoid(f)
                    float igg = (1.0f - b) * frcp((1.0f + a) * (1.0f + b));       // sig(i)*tanh(g)
                    float cn = fmaf(sf, c[mt][r], igg);
                    c[mt][r] = cn;
                    float dd = fexp2(-LOG2E2 * cn);
                    hh[r2] = (1.0f - dd) * frcp((1.0f + cc) * (1.0f + dd));       // sig(o)*tanh(cn)
                }
                const unsigned pk = cvt_pk_bf16(hh[0], hh[1]);
                if (t < T_WIN - 1) {
                    *(unsigned short*)(pnxt + mt * (16 * ASTR) + wroff[rp][0]) = (unsigned short)pk;
                    *(unsigned short*)(pnxt + mt * (16 * ASTR) + wroff[rp][1]) = (unsigned short)(pk >> 16);
                } else {
                    const int node0 = mt * 16 + (lane >> 4) * 4 + rp * 2;
                    hout[(size_t)(n0 + node0) * HID + colw]     = (unsigned short)pk;
                    hout[(size_t)(n0 + node0 + 1) * HID + colw] = (unsigned short)(pk >> 16);
                }
            }
        }

        if (xactive && t + 1 < T_WIN) {
            ushortx4 b;
            b.x = f2bf(xv.x); b.y = f2bf(xv.y); b.z = f2bf(xv.z); b.w = f2bf(xv.w);
            *(ushortx4*)(pnxt + xnode * ASTR + xoff) = b;
        }
        __syncthreads();
    }
}

// ---------------- GEMM2 (MFMA): [xl|xr] = h @ [Wl|Wr]^T + bias, bf16 in/out ----------------
#define G2_BM 64
__global__ __launch_bounds__(256) void gemm2_mfma_kernel(
    const unsigned short* __restrict__ hbf,   // [20000][128] bf16
    const unsigned short* __restrict__ wpk2,  // packed B-frags
    const float* __restrict__ biasc2,         // [1024]
    unsigned short* __restrict__ xl, unsigned short* __restrict__ xr)
{
    __shared__ __align__(16) unsigned char Hs[G2_BM * 256];  // [64 rows][128 bf16], XOR-swizzled
    const int tid  = threadIdx.x;
    const int wave = tid >> 6;
    const int lane = tid & 63;
    const int mb = blockIdx.x >> 2;
    const int nb = blockIdx.x & 3;     // 4 col-blocks of 256 (0,1 -> xl; 2,3 -> xr)
    const int n0 = mb * G2_BM;

#pragma unroll
    for (int q = 0; q < 4; ++q) {
        int fi = tid + q * 256;
        int node = fi >> 4;
        int kb = (fi & 15) * 16;
        ushort8 v = {0, 0, 0, 0, 0, 0, 0, 0};
        if (n0 + node < N_NODES) v = *(const ushort8*)&hbf[(size_t)(n0 + node) * HID + kb / 2];
        *(ushort8*)&Hs[node * 256 + (kb ^ ((node & 7) << 4))] = v;
    }
    __syncthreads();

    const int colt0 = nb * 16 + wave * 4;
    float bias4[4];
#pragma unroll
    for (int ct = 0; ct < 4; ++ct)
        bias4[ct] = biasc2[(colt0 + ct) * 16 + (lane & 15)];

    f32x4 acc[4][4];
#pragma unroll
    for (int mt = 0; mt < 4; ++mt)
#pragma unroll
        for (int ct = 0; ct < 4; ++ct) {
            f32x4 a = {bias4[ct], bias4[ct], bias4[ct], bias4[ct]};
            acc[mt][ct] = a;
        }

#pragma unroll
    for (int kt = 0; kt < 4; ++kt) {
        short8 wf[4];
#pragma unroll
        for (int ct = 0; ct < 4; ++ct)
            wf[ct] = *(const short8*)&wpk2[(((colt0 + ct) * 4 + kt) * 64 + lane) * 8];
        short8 af[4];
        const int kbyte = kt * 64 + (lane >> 4) * 16;
#pragma unroll
        for (int mt = 0; mt < 4; ++mt) {
            int row = mt * 16 + (lane & 15);
            af[mt] = *(const short8*)&Hs[row * 256 + (kbyte ^ ((row & 7) << 4))];
        }
#pragma unroll
        for (int mt = 0; mt < 4; ++mt)
#pragma unroll
            for (int ct = 0; ct < 4; ++ct)
                acc[mt][ct] = __builtin_amdgcn_mfma_f32_16x16x32_bf16(af[mt], wf[ct], acc[mt][ct], 0, 0, 0);
    }

    unsigned short* outp = (nb < 2) ? xl : xr;
    const int lcol = (nb & 1) * 256 + wave * 64 + (lane & 15);
#pragma unroll
    for (int mt = 0; mt < 4; ++mt)
#pragma unroll
        for (int ct = 0; ct < 4; ++ct)
#pragma unroll
            for (int r = 0; r < 4; ++r) {
                int row = n0 + mt * 16 + (lane >> 4) * 4 + r;
                if (row < N_NODES)
                    outp[(size_t)row * G4 + lcol + ct * 16] = f2bf(acc[mt][ct][r]);
            }
}

// ---------------- edge sort (counting sort by dst) ----------------
__global__ void count_kernel(const int* __restrict__ ei, int* __restrict__ cnt)
{
    int e = blockIdx.x * 256 + threadIdx.x;
    if (e < N_EDGES) {
        int dst = ei[N_EDGES + e];
        if (dst >= 0 && dst < N_NODES) atomicAdd(&cnt[dst], 1);
    }
}

#define SCAN_NT 1024
__global__ __launch_bounds__(SCAN_NT) void scan_kernel(const int* __restrict__ cnt, int* __restrict__ base)
{
    __shared__ int ps[SCAN_NT];
    const int tid = threadIdx.x;
    const int CH = (N_NODES + SCAN_NT - 1) / SCAN_NT;  // 20
    int s = 0;
    for (int i = 0; i < CH; ++i) {
        int idx = tid * CH + i;
        if (idx < N_NODES) s += cnt[idx];
    }
    ps[tid] = s;
    __syncthreads();
    for (int off = 1; off < SCAN_NT; off <<= 1) {
        int v = (tid >= off) ? ps[tid - off] : 0;
        __syncthreads();
        ps[tid] += v;
        __syncthreads();
    }
    int run = (tid > 0) ? ps[tid - 1] : 0;
    for (int i = 0; i < CH; ++i) {
        int idx = tid * CH + i;
        if (idx < N_NODES) { base[idx] = run; run += cnt[idx]; }
    }
    if (tid == SCAN_NT - 1) base[N_NODES] = ps[SCAN_NT - 1];
}

__global__ void scatter_kernel(const int* __restrict__ ei, const int* __restrict__ base,
                               int* __restrict__ cnt2, int* __restrict__ srt)
{
    int e = blockIdx.x * 256 + threadIdx.x;
    if (e < N_EDGES) {
        int dst = ei[N_EDGES + e];
        int src = ei[e];
        if (dst >= 0 && dst < N_NODES) {
            int pos = base[dst] + atomicAdd(&cnt2[dst], 1);
            srt[pos] = src;
        }
    }
}

// ---------------- GATv2 aggregate: one wave per dst, online softmax, 4-edge pipeline ----------------
__global__ __launch_bounds__(256) void gat_kernel(
    const unsigned short* __restrict__ xl, const unsigned short* __restrict__ xr,
    const float* __restrict__ att, const float* __restrict__ gbias,
    const float* __restrict__ Wp, const float* __restrict__ bp,
    const int* __restrict__ base, const int* __restrict__ srt,
    float* __restrict__ out)
{
    const int wave = threadIdx.x >> 6;
    const int lane = threadIdx.x & 63;
    const int dst = blockIdx.x * 4 + wave;
    if (dst >= N_NODES) return;

    ushort8 xr8 = *(const ushort8*)&xr[(size_t)dst * G4 + lane * 8];
    float xrv[8];
#pragma unroll
    for (int i = 0; i < 8; ++i) xrv[i] = bf2f(xr8[i]);
    float4 at0 = *(const float4*)&att[lane * 8];
    float4 at1 = *(const float4*)&att[lane * 8 + 4];
    float atv[8] = {at0.x, at0.y, at0.z, at0.w, at1.x, at1.y, at1.z, at1.w};

    float m = -INFINITY, d = 0.0f;
    float acc[8];
#pragma unroll
    for (int i = 0; i < 8; ++i) acc[i] = 0.0f;

    const int b0 = base[dst], b1 = base[dst + 1];
    const int nE = b1 - b0 + 1;          // in-edges + self loop (logical last entry)
    int e = 0;
    // quad loop: 4 gathers in flight; one softmax rescale per quad.
    // within a quad starting at e (e+4<=nE), only slot 3 can be the self loop.
    for (; e + 4 <= nE; e += 4) {
        int s0 = srt[b0 + e];
        int s1 = srt[b0 + e + 1];
        int s2 = srt[b0 + e + 2];
        int s3 = (e + 4 == nE) ? dst : srt[b0 + e + 3];
        ushort8 v0 = *(const ushort8*)&xl[(size_t)s0 * G4 + lane * 8];
        ushort8 v1 = *(const ushort8*)&xl[(size_t)s1 * G4 + lane * 8];
        ushort8 v2 = *(const ushort8*)&xl[(size_t)s2 * G4 + lane * 8];
        ushort8 v3 = *(const ushort8*)&xl[(size_t)s3 * G4 + lane * 8];
        float x0[8], x1[8], x2[8], x3[8];
#pragma unroll
        for (int i = 0; i < 8; ++i) {
            x0[i] = bf2f(v0[i]); x1[i] = bf2f(v1[i]);
            x2[i] = bf2f(v2[i]); x3[i] = bf2f(v3[i]);
        }
        float p0 = 0.0f, p1 = 0.0f, p2 = 0.0f, p3 = 0.0f;
#pragma unroll
        for (int i = 0; i < 8; ++i) {
            float e0 = x0[i] + xrv[i], e1 = x1[i] + xrv[i];
            float e2 = x2[i] + xrv[i], e3 = x3[i] + xrv[i];
            e0 = (e0 > 0.0f) ? e0 : 0.2f * e0;
            e1 = (e1 > 0.0f) ? e1 : 0.2f * e1;
            e2 = (e2 > 0.0f) ? e2 : 0.2f * e2;
            e3 = (e3 > 0.0f) ? e3 : 0.2f * e3;
            p0 = fmaf(atv[i], e0, p0);
            p1 = fmaf(atv[i], e1, p1);
            p2 = fmaf(atv[i], e2, p2);
            p3 = fmaf(atv[i], e3, p3);
        }
#pragma unroll
        for (int sh = 1; sh <= 8; sh <<= 1) {
            p0 += __shfl_xor(p0, sh);
            p1 += __shfl_xor(p1, sh);
            p2 += __shfl_xor(p2, sh);
            p3 += __shfl_xor(p3, sh);
        }
        float mn = fmaxf(fmaxf(m, fmaxf(p0, p1)), fmaxf(p2, p3));
        float scale = __expf(m - mn);
        float a0 = __expf(p0 - mn);
        float a1 = __expf(p1 - mn);
        float a2 = __expf(p2 - mn);
        float a3 = __expf(p3 - mn);
        d = fmaf(d, scale, (a0 + a1) + (a2 + a3));
#pragma unroll
        for (int i = 0; i < 8; ++i)
            acc[i] = fmaf(a3, x3[i], fmaf(a2, x2[i], fmaf(a1, x1[i], fmaf(a0, x0[i], acc[i] * scale))));
        m = mn;
    }
    // remainder: up to 3 single entries (last one is the self loop)
    for (; e < nE; ++e) {
        int src = (e == nE - 1) ? dst : srt[b0 + e];
        ushort8 v8 = *(const ushort8*)&xl[(size_t)src * G4 + lane * 8];
        float xv[8];
#pragma unroll
        for (int i = 0; i < 8; ++i) xv[i] = bf2f(v8[i]);
        float p = 0.0f;
#pragma unroll
        for (int i = 0; i < 8; ++i) {
            float ee = xv[i] + xrv[i];
            ee = (ee > 0.0f) ? ee : 0.2f * ee;
            p = fmaf(atv[i], ee, p);
        }
        p += __shfl_xor(p, 1);
        p += __shfl_xor(p, 2);
        p += __shfl_xor(p, 4);
        p += __shfl_xor(p, 8);
        float mn = fmaxf(m, p);
        float scale = __expf(m - mn);
        float al = __expf(p - mn);
        d = fmaf(d, scale, al);
#pragma unroll
        for (int i = 0; i < 8; ++i) acc[i] = fmaf(al, xv[i], acc[i] * scale);
        m = mn;
    }

    float inv = 1.0f / d;
    float o[8];
#pragma unroll
    for (int i = 0; i < 8; ++i) o[i] = acc[i] * inv;
#pragma unroll
    for (int i = 0; i < 8; ++i) {
        o[i] += __shfl_xor(o[i], 16);
        o[i] += __shfl_xor(o[i], 32);
    }
    const int c0 = (lane & 15) * 8;
    float psum = 0.0f;
#pragma unroll
    for (int i = 0; i < 8; ++i) {
        float s = 0.25f * o[i] + gbias[c0 + i];
        s = (s > 0.0f) ? s : (__expf(s) - 1.0f);
        psum = fmaf(s, Wp[c0 + i], psum);
    }
    psum += __shfl_xor(psum, 1);
    psum += __shfl_xor(psum, 2);
    psum += __shfl_xor(psum, 4);
    psum += __shfl_xor(psum, 8);
    if (lane == 0) out[dst] = psum + bp[0];
}

// ---------------- launch ----------------
extern "C" void kernel_launch(void* const* d_in, const int* in_sizes, int n_in,
                              void* d_out, int out_size, void* d_ws, size_t ws_size,
                              hipStream_t stream)
{
    const float* x        = (const float*)d_in[0];
    const int* ei         = (const int*)d_in[1];     // int32 per harness contract
    const float* Wih      = (const float*)d_in[2];
    const float* Whh      = (const float*)d_in[3];
    const float* bih      = (const float*)d_in[4];
    const float* bhh      = (const float*)d_in[5];
    const float* Wl       = (const float*)d_in[6];
    const float* bl       = (const float*)d_in[7];
    const float* Wr       = (const float*)d_in[8];
    const float* br       = (const float*)d_in[9];
    const float* att      = (const float*)d_in[10];
    const float* gbias    = (const float*)d_in[11];
    const float* Wp       = (const float*)d_in[12];
    const float* bp       = (const float*)d_in[13];
    float* out            = (float*)d_out;

    float* ws             = (float*)d_ws;
    unsigned short* wpk   = (unsigned short*)(ws + WPK_OFF);
    float* bsc            = ws + BIASC_OFF;
    unsigned short* wpk2  = (unsigned short*)(ws + WPK2_OFF);
    float* bsc2           = ws + BIASC2_OFF;
    unsigned short* h     = (unsigned short*)(ws + H_OFF);
    unsigned short* xlb   = (unsigned short*)(ws + XL_OFF);
    unsigned short* xrb   = (unsigned short*)(ws + XR_OFF);
    int* cnt    = (int*)(ws + CNT_OFF);
    int* cnt2   = (int*)(ws + CNT2_OFF);
    int* base   = (int*)(ws + BASE_OFF);
    int* srt    = (int*)(ws + SRT_OFF);

    hipMemsetAsync(cnt, 0, 2 * N_NODES * sizeof(int), stream);

    pack_w_kernel<<<320, 256, 0, stream>>>(Wih, Whh, bih, bhh, wpk, bsc);
    pack_w2_kernel<<<512, 256, 0, stream>>>(Wl, bl, Wr, br, wpk2, bsc2);
    count_kernel<<<(N_EDGES + 255) / 256, 256, 0, stream>>>(ei, cnt);
    scan_kernel<<<1, SCAN_NT, 0, stream>>>(cnt, base);
    scatter_kernel<<<(N_EDGES + 255) / 256, 256, 0, stream>>>(ei, base, cnt2, srt);

    lstm_mfma_kernel<<<N_NODES / BMM, 512, 0, stream>>>(x, wpk, bsc, h);
    gemm2_mfma_kernel<<<((N_NODES + G2_BM - 1) / G2_BM) * 4, 256, 0, stream>>>(h, wpk2, bsc2, xlb, xrb);
    gat_kernel<<<(N_NODES + 3) / 4, 256, 0, stream>>>(xlb, xrb, att, gbias, Wp, bp, base, srt, out);
}

// Round 16
// 348.726 us; speedup vs baseline: 2.6668x; 1.0031x over previous
//
#include <hip/hip_runtime.h>
#include <hip/hip_bf16.h>

#define N_NODES 20000
#define N_EDGES 250000
#define T_WIN   60
#define F_IN    16
#define HID     128
#define G4      512      // 4*HID
#define HEADS   4

// ---------------- ws layout (float offsets) ----------------
#define WPK_OFF    0            // 81920 ushort (LSTM W B-frags)
#define BIASC_OFF  40960        // 512
#define WPK2_OFF   41472        // 131072 ushort (GAT-lin W B-frags) = 65536 floats
#define BIASC2_OFF 107008       // 1024
#define H_OFF      108032       // 20000*128 ushort (bf16 h) = 1,280,000 floats
#define XL_OFF     1388032      // 20000*512 ushort = 5,120,000 floats
#define XR_OFF     6508032      // 20000*512 ushort
#define CNT_OFF    11628032     // 20000 ints
#define CNT2_OFF   11648032     // 20000 ints
#define BASE_OFF   11668032     // 20001 ints
#define SRT_OFF    11688033     // 250000 ints

typedef __attribute__((ext_vector_type(8))) short short8;
typedef __attribute__((ext_vector_type(8))) unsigned short ushort8;
typedef __attribute__((ext_vector_type(4))) float f32x4;
typedef __attribute__((ext_vector_type(4))) unsigned short ushortx4;

#define LOG2E   1.442695041f
#define LOG2E2  2.885390082f

// compiler-known transcendentals ONLY (r7 lesson: inline-asm v_exp_f32 defeats the
// trans-op hazard recognizer -> stale-register reads -> 6.8e-2 corruption).
__device__ __forceinline__ float fexp2(float x) { return __builtin_amdgcn_exp2f(x); }
__device__ __forceinline__ float frcp(float x)  { return __builtin_amdgcn_rcpf(x); }

__device__ __forceinline__ unsigned short f2bf(float f) {
    unsigned u = __float_as_uint(f);
    u += 0x7FFFu + ((u >> 16) & 1u);   // RNE
    return (unsigned short)(u >> 16);
}
__device__ __forceinline__ float bf2f(unsigned short u) {
    return __uint_as_float((unsigned)u << 16);
}
__device__ __forceinline__ unsigned cvt_pk_bf16(float a, float b) {
    unsigned r;
    asm("v_cvt_pk_bf16_f32 %0, %1, %2" : "=v"(r) : "v"(a), "v"(b));
    return r;
}

// ---------------- fused prologue: pack LSTM W + pack GAT W + edge count ----------------
// blocks 0..319    : LSTM W -> B-frags, exp2-prescaled (i,f,o: -log2e; g: -2log2e)
// blocks 320..831  : GAT lin W (Wl|Wr -> [128 k][1024 cols]) -> B-frags
// blocks 832..1808 : counting-sort histogram of edge dst
__global__ void pack_all_kernel(const float* __restrict__ Wih, const float* __restrict__ Whh,
                                const float* __restrict__ bih, const float* __restrict__ bhh,
                                const float* __restrict__ Wl,  const float* __restrict__ bl,
                                const float* __restrict__ Wr,  const float* __restrict__ br,
                                const int* __restrict__ ei,
                                unsigned short* __restrict__ wpk,  float* __restrict__ biasc,
                                unsigned short* __restrict__ wpk2, float* __restrict__ biasc2,
                                int* __restrict__ cnt)
{
    const int b = blockIdx.x;
    if (b < 320) {
        int idx = b * 256 + threadIdx.x;
        if (idx < 81920) {
            int i  = idx & 7;
            int l  = (idx >> 3) & 63;
            int r  = idx >> 9;
            int kt = r % 5;
            int gh = r / 5;
            int ht = gh & 7;
            int g  = gh >> 3;
            int k   = kt * 32 + (l >> 4) * 8 + i;
            int col = g * 128 + ht * 16 + (l & 15);
            float v = 0.0f;
            if (k < 128)      v = Whh[col * 128 + k];
            else if (k < 144) v = Wih[col * 16 + (k - 128)];
            float sc = (g == 2) ? -LOG2E2 : -LOG2E;
            wpk[idx] = f2bf(v * sc);
        }
        if (idx < G4) {
            int g = idx >> 7;
            float sc = (g == 2) ? -LOG2E2 : -LOG2E;
            biasc[idx] = (bih[idx] + bhh[idx]) * sc;
        }
    } else if (b < 832) {
        int idx = (b - 320) * 256 + threadIdx.x;
        if (idx < 131072) {
            int i  = idx & 7;
            int l  = (idx >> 3) & 63;
            int f  = idx >> 9;       // ht*4 + kt
            int kt = f & 3;
            int ht = f >> 2;
            int k   = kt * 32 + (l >> 4) * 8 + i;
            int col = ht * 16 + (l & 15);
            float v = (col < 512) ? Wl[col * 128 + k] : Wr[(col - 512) * 128 + k];
            wpk2[idx] = f2bf(v);
        }
        if (idx < 1024) biasc2[idx] = (idx < 512) ? bl[idx] : br[idx - 512];
    } else {
        int e = (b - 832) * 256 + threadIdx.x;
        if (e < N_EDGES) {
            int dst = ei[N_EDGES + e];
            if (dst >= 0 && dst < N_NODES) atomicAdd(&cnt[dst], 1);
        }
    }
}

// ---------------- LSTM: MFMA bf16, 80 nodes/block, 250 blocks ----------------
// OCCUPANCY VERDICT (r8-r12): 512-thread blocks never co-schedule 2/CU; 1024-thread
// blocks hard-cap at 64 VGPR -> spill. 8 waves @ 512 thr, 1 block/CU is the optimum.
// Time loop unroll 1 ON PURPOSE (r4 spill). Bias as MFMA C-in; exp2-prescaled W;
// precomputed LDS h-write offsets; fused-rcp activations (5 exp2 + 3 rcp/elem).
// r16: s_setprio(1) around MFMA cluster (waves are phase-diverse between barriers).
#define BMM  80
#define ASTR 384
#define PANEL (BMM * ASTR)

__global__ __launch_bounds__(512) void lstm_mfma_kernel(
    const float* __restrict__ x, const unsigned short* __restrict__ wpk,
    const float* __restrict__ biasc, unsigned short* __restrict__ hout)
{
    __shared__ __align__(16) unsigned char Abuf[2][PANEL];
    const int tid  = threadIdx.x;
    const int wave = tid >> 6;
    const int lane = tid & 63;
    const int n0   = blockIdx.x * BMM;

    {
        f32x4 z = {0.0f, 0.0f, 0.0f, 0.0f};
        unsigned char* ab = &Abuf[0][0];
        for (int i = tid; i < 2 * PANEL / 16; i += 512)
            *(f32x4*)&ab[i * 16] = z;
    }

    // persistent B-fragments: wave w owns hid cols [w*16, w*16+16) for all 4 gates
    short8 wf[4][5];
#pragma unroll
    for (int g = 0; g < 4; ++g)
#pragma unroll
        for (int kt = 0; kt < 5; ++kt)
            wf[g][kt] = *(const short8*)&wpk[((((g * 8 + wave) * 5) + kt) * 64 + lane) * 8];

    // bias as MFMA C-in (prescaled at pack time)
    f32x4 bias_c[4];
#pragma unroll
    for (int g = 0; g < 4; ++g) {
        float b = biasc[g * 128 + wave * 16 + (lane & 15)];
        f32x4 a = {b, b, b, b};
        bias_c[g] = a;
    }

    float c[5][4];
#pragma unroll
    for (int mt = 0; mt < 5; ++mt)
#pragma unroll
        for (int r = 0; r < 4; ++r) c[mt][r] = 0.0f;

    const int  xnode   = tid >> 2;
    const int  xq      = tid & 3;
    const bool xactive = (tid < BMM * 4);
    const int  xoff    = (256 + xq * 8) ^ ((xnode & 7) << 4);
    const int  colw    = wave * 16 + (lane & 15);
    const float* xptr  = &x[(size_t)(n0 + xnode) * (T_WIN * F_IN) + xq * 4];

    // precomputed h-write LDS offsets (mt*16 ≡ 0 mod 8 -> swizzle mt-invariant)
    unsigned wroff[2][2];
#pragma unroll
    for (int rp = 0; rp < 2; ++rp)
#pragma unroll
        for (int w = 0; w < 2; ++w) {
            int nd = (lane >> 4) * 4 + rp * 2 + w;
            wroff[rp][w] = nd * ASTR + ((colw * 2) ^ ((nd & 7) << 4));
        }

    __syncthreads();

    if (xactive) {
        float4 v = *(const float4*)xptr;
        ushortx4 b;
        b.x = f2bf(v.x); b.y = f2bf(v.y); b.z = f2bf(v.z); b.w = f2bf(v.w);
        *(ushortx4*)&Abuf[0][xnode * ASTR + xoff] = b;
    }
    __syncthreads();

#pragma unroll 1
    for (int t = 0; t < T_WIN; ++t) {
        const int cur = t & 1;
        const int nxt = cur ^ 1;
        unsigned char* pnxt = &Abuf[nxt][0];

        float4 xv = {0.0f, 0.0f, 0.0f, 0.0f};
        if (xactive && t + 1 < T_WIN) xv = *(const float4*)(xptr + (t + 1) * F_IN);

        // per-mt: ds_read -> 20 MFMA -> activation (act(mt) overlaps MFMA(mt+1))
#pragma unroll
        for (int mt = 0; mt < 5; ++mt) {
            const int row = mt * 16 + (lane & 15);
            const int rsw = (row & 7) << 4;
            short8 af[5];
#pragma unroll
            for (int kt = 0; kt < 5; ++kt)
                af[kt] = *(const short8*)&Abuf[cur][row * ASTR + ((kt * 64 + (lane >> 4) * 16) ^ rsw)];

            __builtin_amdgcn_s_setprio(1);
            f32x4 ag[4];
#pragma unroll
            for (int g = 0; g < 4; ++g)
                ag[g] = __builtin_amdgcn_mfma_f32_16x16x32_bf16(af[0], wf[g][0], bias_c[g], 0, 0, 0);
#pragma unroll
            for (int kt = 1; kt < 5; ++kt)
#pragma unroll
                for (int g = 0; g < 4; ++g)
                    ag[g] = __builtin_amdgcn_mfma_f32_16x16x32_bf16(af[kt], wf[g][kt], ag[g], 0, 0, 0);
            __builtin_amdgcn_s_setprio(0);

#pragma unroll
            for (int rp = 0; rp < 2; ++rp) {
                float hh[2];
#pragma unroll
                for (int r2 = 0; r2 < 2; ++r2) {
                    const int r = rp * 2 + r2;
                    // fused-rcp activations: a=e^-i, fv=e^-f, b=e^-2g, cc=e^-o, dd=e^-2cn
                    float a  = fexp2(ag[0][r]);
                    float fv = fexp2(ag[1][r]);
                    float b  = fexp2(ag[2][r]);
                    float cc = fexp2(ag[3][r]);
                    float sf = frcp(1.0f + fv);                                   // sigmoid(f)
                    float igg = (1.0f - b) * frcp((1.0f + a) * (1.0f + b));       // sig(i)*tanh(g)
                    float cn = fmaf(sf, c[mt][r], igg);
                    c[mt][r] = cn;
                    float dd = fexp2(-LOG2E2 * cn);
                    hh[r2] = (1.0f - dd) * frcp((1.0f + cc) * (1.0f + dd));       // sig(o)*tanh(cn)
                }
                const unsigned pk = cvt_pk_bf16(hh[0], hh[1]);
                if (t < T_WIN - 1) {
                    *(unsigned short*)(pnxt + mt * (16 * ASTR) + wroff[rp][0]) = (unsigned short)pk;
                    *(unsigned short*)(pnxt + mt * (16 * ASTR) + wroff[rp][1]) = (unsigned short)(pk >> 16);
                } else {
                    const int node0 = mt * 16 + (lane >> 4) * 4 + rp * 2;
                    hout[(size_t)(n0 + node0) * HID + colw]     = (unsigned short)pk;
                    hout[(size_t)(n0 + node0 + 1) * HID + colw] = (unsigned short)(pk >> 16);
                }
            }
        }

        if (xactive && t + 1 < T_WIN) {
            ushortx4 b;
            b.x = f2bf(xv.x); b.y = f2bf(xv.y); b.z = f2bf(xv.z); b.w = f2bf(xv.w);
            *(ushortx4*)(pnxt + xnode * ASTR + xoff) = b;
        }
        __syncthreads();
    }
}

// ---------------- GEMM2 (MFMA): [xl|xr] = h @ [Wl|Wr]^T + bias, bf16 in/out ----------------
// r16: nb-loop inside the block -> h tile staged to LDS ONCE for all 4 col-blocks
// (h HBM/L2 traffic 20.5 MB -> 5.1 MB); 313 blocks instead of 1252.
#define G2_BM 64
__global__ __launch_bounds__(256) void gemm2_mfma_kernel(
    const unsigned short* __restrict__ hbf,   // [20000][128] bf16
    const unsigned short* __restrict__ wpk2,  // packed B-frags
    const float* __restrict__ biasc2,         // [1024]
    unsigned short* __restrict__ xl, unsigned short* __restrict__ xr)
{
    __shared__ __align__(16) unsigned char Hs[G2_BM * 256];  // [64 rows][128 bf16], XOR-swizzled
    const int tid  = threadIdx.x;
    const int wave = tid >> 6;
    const int lane = tid & 63;
    const int n0 = blockIdx.x * G2_BM;

#pragma unroll
    for (int q = 0; q < 4; ++q) {
        int fi = tid + q * 256;
        int node = fi >> 4;
        int kb = (fi & 15) * 16;
        ushort8 v = {0, 0, 0, 0, 0, 0, 0, 0};
        if (n0 + node < N_NODES) v = *(const ushort8*)&hbf[(size_t)(n0 + node) * HID + kb / 2];
        *(ushort8*)&Hs[node * 256 + (kb ^ ((node & 7) << 4))] = v;
    }
    __syncthreads();

#pragma unroll 1
    for (int nb = 0; nb < 4; ++nb) {
        const int colt0 = nb * 16 + wave * 4;
        float bias4[4];
#pragma unroll
        for (int ct = 0; ct < 4; ++ct)
            bias4[ct] = biasc2[(colt0 + ct) * 16 + (lane & 15)];

        f32x4 acc[4][4];
#pragma unroll
        for (int mt = 0; mt < 4; ++mt)
#pragma unroll
            for (int ct = 0; ct < 4; ++ct) {
                f32x4 a = {bias4[ct], bias4[ct], bias4[ct], bias4[ct]};
                acc[mt][ct] = a;
            }

#pragma unroll
        for (int kt = 0; kt < 4; ++kt) {
            short8 wf[4];
#pragma unroll
            for (int ct = 0; ct < 4; ++ct)
                wf[ct] = *(const short8*)&wpk2[(((colt0 + ct) * 4 + kt) * 64 + lane) * 8];
            short8 af[4];
            const int kbyte = kt * 64 + (lane >> 4) * 16;
#pragma unroll
            for (int mt = 0; mt < 4; ++mt) {
                int row = mt * 16 + (lane & 15);
                af[mt] = *(const short8*)&Hs[row * 256 + (kbyte ^ ((row & 7) << 4))];
            }
#pragma unroll
            for (int mt = 0; mt < 4; ++mt)
#pragma unroll
                for (int ct = 0; ct < 4; ++ct)
                    acc[mt][ct] = __builtin_amdgcn_mfma_f32_16x16x32_bf16(af[mt], wf[ct], acc[mt][ct], 0, 0, 0);
        }

        unsigned short* outp = (nb < 2) ? xl : xr;
        const int lcol = (nb & 1) * 256 + wave * 64 + (lane & 15);
#pragma unroll
        for (int mt = 0; mt < 4; ++mt)
#pragma unroll
            for (int ct = 0; ct < 4; ++ct)
#pragma unroll
                for (int r = 0; r < 4; ++r) {
                    int row = n0 + mt * 16 + (lane >> 4) * 4 + r;
                    if (row < N_NODES)
                        outp[(size_t)row * G4 + lcol + ct * 16] = f2bf(acc[mt][ct][r]);
                }
    }
}

// ---------------- edge sort: scan + scatter ----------------
#define SCAN_NT 1024
__global__ __launch_bounds__(SCAN_NT) void scan_kernel(const int* __restrict__ cnt, int* __restrict__ base)
{
    __shared__ int ps[SCAN_NT];
    const int tid = threadIdx.x;
    const int CH = (N_NODES + SCAN_NT - 1) / SCAN_NT;  // 20
    int s = 0;
    for (int i = 0; i < CH; ++i) {
        int idx = tid * CH + i;
        if (idx < N_NODES) s += cnt[idx];
    }
    ps[tid] = s;
    __syncthreads();
    for (int off = 1; off < SCAN_NT; off <<= 1) {
        int v = (tid >= off) ? ps[tid - off] : 0;
        __syncthreads();
        ps[tid] += v;
        __syncthreads();
    }
    int run = (tid > 0) ? ps[tid - 1] : 0;
    for (int i = 0; i < CH; ++i) {
        int idx = tid * CH + i;
        if (idx < N_NODES) { base[idx] = run; run += cnt[idx]; }
    }
    if (tid == SCAN_NT - 1) base[N_NODES] = ps[SCAN_NT - 1];
}

__global__ void scatter_kernel(const int* __restrict__ ei, const int* __restrict__ base,
                               int* __restrict__ cnt2, int* __restrict__ srt)
{
    int e = blockIdx.x * 256 + threadIdx.x;
    if (e < N_EDGES) {
        int dst = ei[N_EDGES + e];
        int src = ei[e];
        if (dst >= 0 && dst < N_NODES) {
            int pos = base[dst] + atomicAdd(&cnt2[dst], 1);
            srt[pos] = src;
        }
    }
}

// ---------------- GATv2 aggregate: one wave per dst, online softmax, 4-edge pipeline ----------------
__global__ __launch_bounds__(256) void gat_kernel(
    const unsigned short* __restrict__ xl, const unsigned short* __restrict__ xr,
    const float* __restrict__ att, const float* __restrict__ gbias,
    const float* __restrict__ Wp, const float* __restrict__ bp,
    const int* __restrict__ base, const int* __restrict__ srt,
    float* __restrict__ out)
{
    const int wave = threadIdx.x >> 6;
    const int lane = threadIdx.x & 63;
    const int dst = blockIdx.x * 4 + wave;
    if (dst >= N_NODES) return;

    ushort8 xr8 = *(const ushort8*)&xr[(size_t)dst * G4 + lane * 8];
    float xrv[8];
#pragma unroll
    for (int i = 0; i < 8; ++i) xrv[i] = bf2f(xr8[i]);
    float4 at0 = *(const float4*)&att[lane * 8];
    float4 at1 = *(const float4*)&att[lane * 8 + 4];
    float atv[8] = {at0.x, at0.y, at0.z, at0.w, at1.x, at1.y, at1.z, at1.w};

    float m = -INFINITY, d = 0.0f;
    float acc[8];
#pragma unroll
    for (int i = 0; i < 8; ++i) acc[i] = 0.0f;

    const int b0 = base[dst], b1 = base[dst + 1];
    const int nE = b1 - b0 + 1;          // in-edges + self loop (logical last entry)
    int e = 0;
    // quad loop: 4 gathers in flight; one softmax rescale per quad.
    for (; e + 4 <= nE; e += 4) {
        int s0 = srt[b0 + e];
        int s1 = srt[b0 + e + 1];
        int s2 = srt[b0 + e + 2];
        int s3 = (e + 4 == nE) ? dst : srt[b0 + e + 3];
        ushort8 v0 = *(const ushort8*)&xl[(size_t)s0 * G4 + lane * 8];
        ushort8 v1 = *(const ushort8*)&xl[(size_t)s1 * G4 + lane * 8];
        ushort8 v2 = *(const ushort8*)&xl[(size_t)s2 * G4 + lane * 8];
        ushort8 v3 = *(const ushort8*)&xl[(size_t)s3 * G4 + lane * 8];
        float x0[8], x1[8], x2[8], x3[8];
#pragma unroll
        for (int i = 0; i < 8; ++i) {
            x0[i] = bf2f(v0[i]); x1[i] = bf2f(v1[i]);
            x2[i] = bf2f(v2[i]); x3[i] = bf2f(v3[i]);
        }
        float p0 = 0.0f, p1 = 0.0f, p2 = 0.0f, p3 = 0.0f;
#pragma unroll
        for (int i = 0; i < 8; ++i) {
            float e0 = x0[i] + xrv[i], e1 = x1[i] + xrv[i];
            float e2 = x2[i] + xrv[i], e3 = x3[i] + xrv[i];
            e0 = (e0 > 0.0f) ? e0 : 0.2f * e0;
            e1 = (e1 > 0.0f) ? e1 : 0.2f * e1;
            e2 = (e2 > 0.0f) ? e2 : 0.2f * e2;
            e3 = (e3 > 0.0f) ? e3 : 0.2f * e3;
            p0 = fmaf(atv[i], e0, p0);
            p1 = fmaf(atv[i], e1, p1);
            p2 = fmaf(atv[i], e2, p2);
            p3 = fmaf(atv[i], e3, p3);
        }
#pragma unroll
        for (int sh = 1; sh <= 8; sh <<= 1) {
            p0 += __shfl_xor(p0, sh);
            p1 += __shfl_xor(p1, sh);
            p2 += __shfl_xor(p2, sh);
            p3 += __shfl_xor(p3, sh);
        }
        float mn = fmaxf(fmaxf(m, fmaxf(p0, p1)), fmaxf(p2, p3));
        float scale = __expf(m - mn);
        float a0 = __expf(p0 - mn);
        float a1 = __expf(p1 - mn);
        float a2 = __expf(p2 - mn);
        float a3 = __expf(p3 - mn);
        d = fmaf(d, scale, (a0 + a1) + (a2 + a3));
#pragma unroll
        for (int i = 0; i < 8; ++i)
            acc[i] = fmaf(a3, x3[i], fmaf(a2, x2[i], fmaf(a1, x1[i], fmaf(a0, x0[i], acc[i] * scale))));
        m = mn;
    }
    // remainder: up to 3 single entries (last one is the self loop)
    for (; e < nE; ++e) {
        int src = (e == nE - 1) ? dst : srt[b0 + e];
        ushort8 v8 = *(const ushort8*)&xl[(size_t)src * G4 + lane * 8];
        float xv[8];
#pragma unroll
        for (int i = 0; i < 8; ++i) xv[i] = bf2f(v8[i]);
        float p = 0.0f;
#pragma unroll
        for (int i = 0; i < 8; ++i) {
            float ee = xv[i] + xrv[i];
            ee = (ee > 0.0f) ? ee : 0.2f * ee;
            p = fmaf(atv[i], ee, p);
        }
        p += __shfl_xor(p, 1);
        p += __shfl_xor(p, 2);
        p += __shfl_xor(p, 4);
        p += __shfl_xor(p, 8);
        float mn = fmaxf(m, p);
        float scale = __expf(m - mn);
        float al = __expf(p - mn);
        d = fmaf(d, scale, al);
#pragma unroll
        for (int i = 0; i < 8; ++i) acc[i] = fmaf(al, xv[i], acc[i] * scale);
        m = mn;
    }

    float inv = 1.0f / d;
    float o[8];
#pragma unroll
    for (int i = 0; i < 8; ++i) o[i] = acc[i] * inv;
#pragma unroll
    for (int i = 0; i < 8; ++i) {
        o[i] += __shfl_xor(o[i], 16);
        o[i] += __shfl_xor(o[i], 32);
    }
    const int c0 = (lane & 15) * 8;
    float psum = 0.0f;
#pragma unroll
    for (int i = 0; i < 8; ++i) {
        float s = 0.25f * o[i] + gbias[c0 + i];
        s = (s > 0.0f) ? s : (__expf(s) - 1.0f);
        psum = fmaf(s, Wp[c0 + i], psum);
    }
    psum += __shfl_xor(psum, 1);
    psum += __shfl_xor(psum, 2);
    psum += __shfl_xor(psum, 4);
    psum += __shfl_xor(psum, 8);
    if (lane == 0) out[dst] = psum + bp[0];
}

// ---------------- launch ----------------
extern "C" void kernel_launch(void* const* d_in, const int* in_sizes, int n_in,
                              void* d_out, int out_size, void* d_ws, size_t ws_size,
                              hipStream_t stream)
{
    const float* x        = (const float*)d_in[0];
    const int* ei         = (const int*)d_in[1];     // int32 per harness contract
    const float* Wih      = (const float*)d_in[2];
    const float* Whh      = (const float*)d_in[3];
    const float* bih      = (const float*)d_in[4];
    const float* bhh      = (const float*)d_in[5];
    const float* Wl       = (const float*)d_in[6];
    const float* bl       = (const float*)d_in[7];
    const float* Wr       = (const float*)d_in[8];
    const float* br       = (const float*)d_in[9];
    const float* att      = (const float*)d_in[10];
    const float* gbias    = (const float*)d_in[11];
    const float* Wp       = (const float*)d_in[12];
    const float* bp       = (const float*)d_in[13];
    float* out            = (float*)d_out;

    float* ws             = (float*)d_ws;
    unsigned short* wpk   = (unsigned short*)(ws + WPK_OFF);
    float* bsc            = ws + BIASC_OFF;
    unsigned short* wpk2  = (unsigned short*)(ws + WPK2_OFF);
    float* bsc2           = ws + BIASC2_OFF;
    unsigned short* h     = (unsigned short*)(ws + H_OFF);
    unsigned short* xlb   = (unsigned short*)(ws + XL_OFF);
    unsigned short* xrb   = (unsigned short*)(ws + XR_OFF);
    int* cnt    = (int*)(ws + CNT_OFF);
    int* cnt2   = (int*)(ws + CNT2_OFF);
    int* base   = (int*)(ws + BASE_OFF);
    int* srt    = (int*)(ws + SRT_OFF);

    hipMemsetAsync(cnt, 0, 2 * N_NODES * sizeof(int), stream);

    const int CNT_BLOCKS = (N_EDGES + 255) / 256;                 // 977
    pack_all_kernel<<<832 + CNT_BLOCKS, 256, 0, stream>>>(
        Wih, Whh, bih, bhh, Wl, bl, Wr, br, ei, wpk, bsc, wpk2, bsc2, cnt);
    scan_kernel<<<1, SCAN_NT, 0, stream>>>(cnt, base);
    scatter_kernel<<<CNT_BLOCKS, 256, 0, stream>>>(ei, base, cnt2, srt);

    lstm_mfma_kernel<<<N_NODES / BMM, 512, 0, stream>>>(x, wpk, bsc, h);
    gemm2_mfma_kernel<<<(N_NODES + G2_BM - 1) / G2_BM, 256, 0, stream>>>(h, wpk2, bsc2, xlb, xrb);
    gat_kernel<<<(N_NODES + 3) / 4, 256, 0, stream>>>(xlb, xrb, att, gbias, Wp, bp, base, srt, out);
}